// Round 25
// baseline (167.706 us; speedup 1.0000x reference)
//
#include <hip/hip_runtime.h>
#include <hip/hip_bf16.h>
#include <math.h>

#define H_     8
#define DK_    64
#define INNER_ 512
#define B_     8
#define T_     1024
#define D_     512
#define PLEN_  2047
#define BT_    8192

typedef __attribute__((ext_vector_type(8))) short bf16x8;
typedef __attribute__((ext_vector_type(4))) float f32x4;
typedef __attribute__((ext_vector_type(4))) unsigned short u16x4;
typedef __attribute__((ext_vector_type(8))) unsigned short u16x8;

__device__ __forceinline__ unsigned short f2bf(float f) {
    unsigned u = __float_as_uint(f);
    u += 0x7fffu + ((u >> 16) & 1u);
    return (unsigned short)(u >> 16);
}
__device__ __forceinline__ float bf2f(unsigned short s) {
    return __uint_as_float(((unsigned)s) << 16);
}
__device__ __forceinline__ f32x4 mfma16(bf16x8 a, bf16x8 b, f32x4 c) {
    return __builtin_amdgcn_mfma_f32_16x16x32_bf16(a, b, c, 0, 0, 0);
}
__device__ __forceinline__ void gload16(const unsigned short* g, unsigned short* l) {
    __builtin_amdgcn_global_load_lds(
        (const __attribute__((address_space(1))) void*)g,
        (__attribute__((address_space(3))) void*)l,
        16, 0, 0);
}
#define BARRIER()  __builtin_amdgcn_s_barrier()
#define SCHEDBAR() __builtin_amdgcn_sched_barrier(0)
#define VMCNT(N)   asm volatile("s_waitcnt vmcnt(" #N ")" ::: "memory")

#define QSCALE 0.125f

// ---------------------------------------------------------------------------
// prep_all: ONE dispatch for all preps.
// ---------------------------------------------------------------------------
struct PrepAll {
    const float* s[4];
    unsigned short* h[4];
    unsigned short* l[4];
    long n[4];
    int wantl[4];
    const float* w[5];
    unsigned short* wh[5];
    unsigned short* wl[5];
    const float* b_ao;
    const float* w_o;
    const float* b_o;
    float* be;
    unsigned short* pb_base;
};
__global__ __launch_bounds__(256) void prep_all(PrepAll a)
{
    const int y = blockIdx.y;
    const int t = threadIdx.x;
    if (y < 4) {
        long i4 = ((long)blockIdx.x * 256 + t) * 4;
        if (i4 >= a.n[y]) return;
        f32x4 v = *(const f32x4*)(a.s[y] + i4);
        u16x4 hh, ll;
        #pragma unroll
        for (int i = 0; i < 4; ++i) {
            unsigned short hb = f2bf(v[i]);
            hh[i] = hb;
            ll[i] = f2bf(v[i] - bf2f(hb));
        }
        *(u16x4*)(a.h[y] + i4) = hh;
        if (a.wantl[y]) *(u16x4*)(a.l[y] + i4) = ll;
        return;
    }
    const int x = blockIdx.x;
    if (x < 1280) {
        __shared__ float sW[32][36];
        const int z = x >> 8, idx = x & 255;
        const int n0 = (idx & 15) * 32, k0 = (idx >> 4) * 32;
        const float* w = a.w[z];
        unsigned short* wh = a.wh[z];
        unsigned short* wl = a.wl[z];
        {
            int kr = t >> 3, c4 = (t & 7) * 4;
            f32x4 v = *(const f32x4*)(w + (size_t)(k0 + kr) * 512 + n0 + c4);
            #pragma unroll
            for (int i = 0; i < 4; ++i) sW[kr][c4 + i] = v[i];
        }
        __syncthreads();
        {
            int nr = t >> 3, kc = (t & 7) * 4;
            u16x4 hv, lv;
            #pragma unroll
            for (int i = 0; i < 4; ++i) {
                float f = sW[kc + i][nr];
                unsigned short hb = f2bf(f);
                hv[i] = hb;
                lv[i] = f2bf(f - bf2f(hb));
            }
            *(u16x4*)(wh + (size_t)(n0 + nr) * 512 + k0 + kc) = hv;
            *(u16x4*)(wl + (size_t)(n0 + nr) * 512 + k0 + kc) = lv;
        }
        return;
    }
    if (x < 1282) {
        int n = (x - 1280) * 256 + t;
        float s = a.b_o[n];
        for (int j = 0; j < 512; ++j) s += a.b_ao[j] * a.w_o[(size_t)j * 512 + n];
        a.be[n] = s;
    } else if (x == 1282) {
        ((unsigned int*)a.pb_base)[t] = 0u;
    }
}

// ---------------------------------------------------------------------------
// gemm_core: counted-vmcnt double-barrier pipeline (r11/r14/r16/r17-proven).
// ---------------------------------------------------------------------------
template<int MF, bool ALO, int NJ>
__device__ __forceinline__ void gemm_core(
    f32x4 (&acc)[MF][NJ],
    const unsigned short* __restrict__ Ah_g,
    const unsigned short* __restrict__ Al_g, int lda,
    const unsigned short* __restrict__ Wh_g,
    const unsigned short* __restrict__ Wl_g, int ldw,
    int M, int row0, int col0,
    unsigned short* sAh, unsigned short* sAl,
    unsigned short* sWh, unsigned short* sWl)
{
    const int t = threadIdx.x;
    const int lane = t & 63, w = t >> 6;
    const int wm = w >> 1, wn = w & 1;
    const int ln15 = lane & 15, g4 = lane >> 4;
    const int ASZ = MF * 32 * 32;
    const int WSZ = NJ * 32 * 32;
    constexpr int NLD = (MF / 2) * (ALO ? 2 : 1) + (NJ / 2) * 2;

    auto stage = [&](int kt, int buf) {
        #pragma unroll
        for (int l = 0; l < MF / 2; ++l) {
            int e = l * 256 + w * 64 + lane;
            int row = e >> 2, slot = e & 3;
            int ss = slot ^ (row & 3);
            int gr = row0 + row;
            if (gr > M - 1) gr = M - 1;
            size_t ga = (size_t)gr * lda + kt * 32 + ss * 8;
            gload16(Ah_g + ga, sAh + buf * ASZ + (l * 256 + w * 64) * 8);
            if constexpr (ALO)
                gload16(Al_g + ga, sAl + buf * ASZ + (l * 256 + w * 64) * 8);
        }
        #pragma unroll
        for (int l = 0; l < NJ / 2; ++l) {
            int e = l * 256 + w * 64 + lane;
            int row = e >> 2, slot = e & 3;
            int ss = slot ^ (row & 3);
            size_t gw = (size_t)(col0 + row) * ldw + kt * 32 + ss * 8;
            gload16(Wh_g + gw, sWh + buf * WSZ + (l * 256 + w * 64) * 8);
            gload16(Wl_g + gw, sWl + buf * WSZ + (l * 256 + w * 64) * 8);
        }
    };
    auto comp = [&](int buf) {
        bf16x8 fah[MF], fal[MF], fwh[NJ], fwl[NJ];
        #pragma unroll
        for (int i = 0; i < MF; ++i) {
            int ar = wm * (MF * 16) + i * 16 + ln15;
            int sa = (g4 ^ (ar & 3)) * 8;
            fah[i] = *(const bf16x8*)&sAh[buf * ASZ + ar * 32 + sa];
            if constexpr (ALO)
                fal[i] = *(const bf16x8*)&sAl[buf * ASZ + ar * 32 + sa];
        }
        #pragma unroll
        for (int j = 0; j < NJ; ++j) {
            int wr = wn * (NJ * 16) + j * 16 + ln15;
            int sw = (g4 ^ (wr & 3)) * 8;
            fwh[j] = *(const bf16x8*)&sWh[buf * WSZ + wr * 32 + sw];
            fwl[j] = *(const bf16x8*)&sWl[buf * WSZ + wr * 32 + sw];
        }
        __builtin_amdgcn_s_setprio(1);
        #pragma unroll
        for (int mi = 0; mi < MF; ++mi)
            #pragma unroll
            for (int ni = 0; ni < NJ; ++ni) {
                acc[mi][ni] = mfma16(fah[mi], fwh[ni], acc[mi][ni]);
                acc[mi][ni] = mfma16(fah[mi], fwl[ni], acc[mi][ni]);
                if constexpr (ALO)
                    acc[mi][ni] = mfma16(fal[mi], fwh[ni], acc[mi][ni]);
            }
        __builtin_amdgcn_s_setprio(0);
    };

    stage(0, 0);
    for (int k2 = 0; k2 < 8; ++k2) {
        BARRIER();
        stage(2 * k2 + 1, 1);
        if constexpr (NLD == 6) { VMCNT(6); }
        else if constexpr (NLD == 5) { VMCNT(5); }
        else if constexpr (NLD == 4) { VMCNT(4); }
        else { VMCNT(8); }
        BARRIER(); SCHEDBAR();
        comp(0);
        BARRIER();
        if (k2 < 7) {
            stage(2 * k2 + 2, 0);
            if constexpr (NLD == 6) { VMCNT(6); }
            else if constexpr (NLD == 5) { VMCNT(5); }
            else if constexpr (NLD == 4) { VMCNT(4); }
            else { VMCNT(8); }
        } else {
            VMCNT(0);
        }
        BARRIER(); SCHEDBAR();
        comp(1);
    }
}

#define GEMM_LDS3(MF, NJ) \
    __shared__ __align__(16) unsigned short sAh[2][MF * 32 * 32]; \
    __shared__ __align__(16) unsigned short sAl[2][MF * 32 * 32]; \
    __shared__ __align__(16) unsigned short sWh[2][NJ * 32 * 32]; \
    __shared__ __align__(16) unsigned short sWl[2][NJ * 32 * 32];
#define GEMM_LDS2(MF, NJ) \
    __shared__ __align__(16) unsigned short sAh[2][MF * 32 * 32]; \
    __shared__ __align__(16) unsigned short sWh[2][NJ * 32 * 32]; \
    __shared__ __align__(16) unsigned short sWl[2][NJ * 32 * 32];

// ---- merged QKV + POS projection GEMM; 1D grid 832 = 8 XCDs x (8 rows x 13
// cols): XCD-contiguous row blocks make each A panel L2-exclusive ----
__global__ __launch_bounds__(256, 3) void gemm_qkvp(
    const unsigned short* __restrict__ Ah_g,
    const unsigned short* __restrict__ Wh_g,
    const unsigned short* __restrict__ Wl_g,
    const unsigned short* __restrict__ posh,
    const unsigned short* __restrict__ wp_h,
    const unsigned short* __restrict__ wp_l,
    const float* __restrict__ b_q, const float* __restrict__ bu,
    const float* __restrict__ bv, const float* __restrict__ b_k,
    const float* __restrict__ b_v,
    unsigned short* __restrict__ qu, unsigned short* __restrict__ qv,
    unsigned short* __restrict__ kb, unsigned short* __restrict__ vt,
    unsigned short* __restrict__ pb0)
{
    GEMM_LDS2(4, 4)
    f32x4 acc[4][4];
    #pragma unroll
    for (int i = 0; i < 4; ++i)
        #pragma unroll
        for (int j = 0; j < 4; ++j) acc[i][j] = (f32x4){0.f, 0.f, 0.f, 0.f};

    const int lin = blockIdx.x;                 // 0..831
    const int wgid = (lin & 7) * 104 + (lin >> 3);   // bijective: 832 = 8*104
    const int bx = wgid % 13, by = wgid / 13;
    const bool isPos = (bx == 12);
    int row0, col0, M;
    const unsigned short *Ag, *Whg, *Wlg;
    if (isPos) {
        row0 = (by >> 2) * 128; col0 = (by & 3) * 128;
        Ag = posh; Whg = wp_h; Wlg = wp_l; M = PLEN_;
    } else {
        row0 = by * 128; col0 = bx * 128;
        Ag = Ah_g; Whg = Wh_g; Wlg = Wl_g; M = BT_;
    }
    gemm_core<4, false, 4>(acc, Ag, nullptr, 512, Whg, Wlg, 512, M, row0, col0,
                           &sAh[0][0], &sAh[0][0], &sWh[0][0], &sWl[0][0]);

    const int t = threadIdx.x;
    const int lane = t & 63, w = t >> 6;
    const int wm = w >> 1, wn = w & 1;
    const int ln15 = lane & 15, g4 = lane >> 4;

    if (isPos) {
        #pragma unroll
        for (int mi = 0; mi < 4; ++mi)
            #pragma unroll
            for (int r4 = 0; r4 < 4; ++r4) {
                int gr = row0 + wm * 64 + mi * 16 + g4 * 4 + r4;
                if (gr >= PLEN_) continue;
                #pragma unroll
                for (int ni = 0; ni < 4; ++ni) {
                    int gc = col0 + wn * 64 + ni * 16 + ln15;
                    pb0[(size_t)gr * 512 + gc] = f2bf(acc[mi][ni][r4]);
                }
            }
        return;
    }

    const int grp = col0 >> 9;   // 0=q, 1=k, 2=v (block-uniform)
    if (grp == 2) {
        #pragma unroll
        for (int mi = 0; mi < 4; ++mi) {
            int gr0 = row0 + wm * 64 + mi * 16 + g4 * 4;
            int bb = gr0 >> 10, t0 = gr0 & 1023;
            #pragma unroll
            for (int ni = 0; ni < 4; ++ni) {
                int gcl = (col0 & 511) + wn * 64 + ni * 16 + ln15;
                float bias = b_v[gcl];
                u16x4 vv;
                #pragma unroll
                for (int r4 = 0; r4 < 4; ++r4) vv[r4] = f2bf(acc[mi][ni][r4] + bias);
                *(u16x4*)(vt + ((size_t)(bb * 512 + gcl)) * 1024 + t0) = vv;
            }
        }
    } else {
        #pragma unroll
        for (int mi = 0; mi < 4; ++mi)
            #pragma unroll
            for (int r4 = 0; r4 < 4; ++r4) {
                int gr = row0 + wm * 64 + mi * 16 + g4 * 4 + r4;
                #pragma unroll
                for (int ni = 0; ni < 4; ++ni) {
                    int gcl = (col0 & 511) + wn * 64 + ni * 16 + ln15;
                    float a = acc[mi][ni][r4];
                    if (grp == 0) {
                        float base = a + b_q[gcl];
                        qu[(size_t)gr * 512 + gcl] = f2bf((base + bu[gcl]) * QSCALE);
                        qv[(size_t)gr * 512 + gcl] = f2bf((base + bv[gcl]) * QSCALE);
                    } else {
                        kb[(size_t)gr * 512 + gcl] = f2bf(a + b_k[gcl]);
                    }
                }
            }
    }
}

// ---- transposed effective-weight GEMMs: 64x64 tiles (256 blocks) ----
struct WeffT {
    const unsigned short* ah[4];
    const unsigned short* al[4];
    const unsigned short* wh[4];
    const unsigned short* wl[4];
    int ldw[4];
    unsigned short* ch[4];
    unsigned short* cl[4];
};
__global__ __launch_bounds__(256, 3) void gemm_wefft(WeffT a)
{
    GEMM_LDS3(2, 2)
    const int z = blockIdx.z;
    f32x4 acc[2][2];
    #pragma unroll
    for (int i = 0; i < 2; ++i)
        #pragma unroll
        for (int j = 0; j < 2; ++j) acc[i][j] = (f32x4){0.f, 0.f, 0.f, 0.f};
    const int row0 = blockIdx.y * 64, col0 = blockIdx.x * 64;
    gemm_core<2, true, 2>(acc, a.ah[z], a.al[z], 512, a.wh[z], a.wl[z], a.ldw[z],
                          512, row0, col0,
                          &sAh[0][0], &sAl[0][0], &sWh[0][0], &sWl[0][0]);

    const int t = threadIdx.x;
    const int lane = t & 63, w = t >> 6;
    const int wm = w >> 1, wn = w & 1;
    const int ln15 = lane & 15, g4 = lane >> 4;
    unsigned short* Ch = a.ch[z];
    unsigned short* Cl = a.cl[z];
    #pragma unroll
    for (int mi = 0; mi < 2; ++mi)
        #pragma unroll
        for (int r4 = 0; r4 < 4; ++r4) {
            int gr = row0 + wm * 32 + mi * 16 + g4 * 4 + r4;
            #pragma unroll
            for (int ni = 0; ni < 2; ++ni) {
                int gc = col0 + wn * 32 + ni * 16 + ln15;
                float v = acc[mi][ni][r4];
                unsigned short hb = f2bf(v);
                Ch[(size_t)gr * 512 + gc] = hb;
                Cl[(size_t)gr * 512 + gc] = f2bf(v - bf2f(hb));
            }
        }
}

// ---- output GEMM: 64x128 tiles, 2-term; 1D grid 512 = 8 XCDs x (16r x 4c) ----
__global__ __launch_bounds__(256, 3) void gemm_out(
    const unsigned short* __restrict__ Ah_g,
    const unsigned short* __restrict__ Wh_g,
    const unsigned short* __restrict__ Wl_g,
    const float* __restrict__ beff, float* __restrict__ C)
{
    GEMM_LDS2(2, 4)
    f32x4 acc[2][4];
    #pragma unroll
    for (int i = 0; i < 2; ++i)
        #pragma unroll
        for (int j = 0; j < 4; ++j) acc[i][j] = (f32x4){0.f, 0.f, 0.f, 0.f};
    const int lin = blockIdx.x;                 // 0..511
    const int wgid = (lin & 7) * 64 + (lin >> 3);    // bijective: 512 = 8*64
    const int row0 = (wgid >> 2) * 64, col0 = (wgid & 3) * 128;
    gemm_core<2, false, 4>(acc, Ah_g, nullptr, 512, Wh_g, Wl_g, 512, BT_, row0, col0,
                           &sAh[0][0], &sAh[0][0], &sWh[0][0], &sWl[0][0]);

    const int t = threadIdx.x;
    const int lane = t & 63, w = t >> 6;
    const int wm = w >> 1, wn = w & 1;
    const int ln15 = lane & 15, g4 = lane >> 4;
    #pragma unroll
    for (int mi = 0; mi < 2; ++mi)
        #pragma unroll
        for (int r4 = 0; r4 < 4; ++r4) {
            int gr = row0 + wm * 32 + mi * 16 + g4 * 4 + r4;
            #pragma unroll
            for (int ni = 0; ni < 4; ++ni) {
                int gc = col0 + wn * 64 + ni * 16 + ln15;
                C[(size_t)gr * 512 + gc] = acc[mi][ni][r4] + beff[gc];
            }
        }
}

// ---------------------------------------------------------------------------
// attn_v16: final form (KVBLK=64, 2 blocks/CU dbuf, __expf, f2bf, single-bf16
// output, XCD-aware swizzle, T13 defer-max). r24-proven.
// ---------------------------------------------------------------------------
__global__ __launch_bounds__(256, 2) void attn_v16(
    const unsigned short* __restrict__ qu_g,
    const unsigned short* __restrict__ qv_g,
    const unsigned short* __restrict__ kb_g,
    const unsigned short* __restrict__ vt_g,
    const unsigned short* __restrict__ pb_g,   // p=0 (zeroed 512-slack before)
    unsigned short* __restrict__ atth)
{
    __shared__ __align__(16) unsigned short sK[2][64 * 64];
    __shared__ __align__(16) unsigned short sP[2][64 * 64];
    __shared__ __align__(16) unsigned short sV[2][64 * 64];   // [d][token]
    __shared__ __align__(16) unsigned short ringb[64][132];   // rotated bf16 ring
    __shared__ __align__(16) unsigned short sProb[64][72];    // [q][k]

    const int t = threadIdx.x;
    const int lane = t & 63, w = t >> 6;
    const int ln15 = lane & 15, g4 = lane >> 4;

    const int wg = blockIdx.x;
    const int idx = (wg & 7) * 128 + (wg >> 3);   // XCD-aware (r18-proven)
    const int q0 = (idx & 15) * 64;
    const int bh = idx >> 4;
    const int h = bh & 7, b = bh >> 3;
    const size_t tok0 = (size_t)b * T_;
    const int hd = h * DK_;
    const int qq = w * 16 + ln15;

    auto stage_chunk = [&](int c, int buf) {
        #pragma unroll
        for (int l = 0; l < 2; ++l) {
            int e = l * 256 + w * 64 + lane;
            int row = e >> 3, slot = e & 7;
            int sl = slot ^ (row & 7);
            int lofs = buf * 4096 + (l * 256 + w * 64) * 8;
            gload16(kb_g + (tok0 + c * 64 + row) * INNER_ + hd + sl * 8, &sK[0][lofs]);
            gload16(vt_g + ((size_t)(b * H_ + h) * DK_ + row) * T_ + c * 64 + sl * 8, &sV[0][lofs]);
            long p = (long)(c * 64 - q0 + 1023 + row);
            gload16(pb_g + p * INNER_ + hd + sl * 8, &sP[0][lofs]);
        }
    };

    // ---- stage Qu -> sK[0], Qv -> sP[0]; pull fragments ----
    #pragma unroll
    for (int l = 0; l < 2; ++l) {
        int e = l * 256 + w * 64 + lane;
        int row = e >> 3, slot = e & 7;
        int sl = slot ^ (row & 7);
        size_t src = (tok0 + q0 + row) * INNER_ + hd + sl * 8;
        gload16(qu_g + src, &sK[0][(l * 256 + w * 64) * 8]);
        gload16(qv_g + src, &sP[0][(l * 256 + w * 64) * 8]);
    }
    __syncthreads();
    bf16x8 fqu[2], fqv[2];
    #pragma unroll
    for (int ki = 0; ki < 2; ++ki) {
        int sl = (ki * 4 + g4) ^ (qq & 7);
        fqu[ki] = *(const bf16x8*)&sK[0][qq * 64 + sl * 8];
        fqv[ki] = *(const bf16x8*)&sP[0][qq * 64 + sl * 8];
    }
    __syncthreads();   // frag ds_reads drained before buffers overwritten

    // ---- stage prologue-P window -> sP[1] AND chunk0 -> buf0 ----
    #pragma unroll
    for (int l = 0; l < 2; ++l) {
        int e = l * 256 + w * 64 + lane;
        int row = e >> 3, slot = e & 7;
        int sl = slot ^ (row & 7);
        long p = (long)(959 - q0 + row);
        gload16(pb_g + p * INNER_ + hd + sl * 8, &sP[0][4096 + (l * 256 + w * 64) * 8]);
    }
    stage_chunk(0, 0);
    __syncthreads();

    // ---- ring prologue (rotated by qq) ----
    #pragma unroll
    for (int n = 0; n < 4; ++n) {
        f32x4 bdv = {0.f, 0.f, 0.f, 0.f};
        #pragma unroll
        for (int ki = 0; ki < 2; ++ki) {
            int prow = n * 16 + ln15;
            int sl = (ki * 4 + g4) ^ (prow & 7);
            bf16x8 pf = *(const bf16x8*)&sP[0][4096 + prow * 64 + sl * 8];
            bdv = mfma16(pf, fqv[ki], bdv);
        }
        #pragma unroll
        for (int r4 = 0; r4 < 4; ++r4)
            ringb[qq][(n * 16 + g4 * 4 + r4 + qq) & 127] = f2bf(bdv[r4]);
    }
    __syncthreads();   // sP[1] free for chunk-1 prefetch

    float m = -1e30f, den = 0.f;
    f32x4 o[4];
    #pragma unroll
    for (int i = 0; i < 4; ++i) o[i] = (f32x4){0.f, 0.f, 0.f, 0.f};

    auto compute_chunk = [&](int c, int buf) {
        const int bofs = buf * 4096;
        f32x4 sc[4], bd[4];
        #pragma unroll
        for (int n = 0; n < 4; ++n) {
            sc[n] = (f32x4){0.f, 0.f, 0.f, 0.f};
            bd[n] = (f32x4){0.f, 0.f, 0.f, 0.f};
        }
        __builtin_amdgcn_s_setprio(1);
        #pragma unroll
        for (int ki = 0; ki < 2; ++ki)
            #pragma unroll
            for (int n = 0; n < 4; ++n) {
                int krow = n * 16 + ln15;
                int sl = (ki * 4 + g4) ^ (krow & 7);
                bf16x8 kf = *(const bf16x8*)&sK[0][bofs + krow * 64 + sl * 8];
                sc[n] = mfma16(kf, fqu[ki], sc[n]);
                bf16x8 pf = *(const bf16x8*)&sP[0][bofs + krow * 64 + sl * 8];
                bd[n] = mfma16(pf, fqv[ki], bd[n]);
            }
        __builtin_amdgcn_s_setprio(0);

        // ring write (rotated; f2bf)
        const int pbase = (c & 1) ? 0 : 64;
        #pragma unroll
        for (int n = 0; n < 4; ++n)
            #pragma unroll
            for (int r4 = 0; r4 < 4; ++r4)
                ringb[qq][(pbase + n * 16 + g4 * 4 + r4 + qq) & 127] = f2bf(bd[n][r4]);

        // scores + online softmax (T13 defer-max: rescale only when needed)
        float s[4][4];
        float mx = -1e30f;
        #pragma unroll
        for (int n = 0; n < 4; ++n) {
            const int st2 = (c * 64 + 64 + n * 16 + g4 * 4) & 127;
            u16x4 rv = *(const u16x4*)&ringb[qq][st2];
            #pragma unroll
            for (int r4 = 0; r4 < 4; ++r4) {
                float v = sc[n][r4] + bf2f(rv[r4]);
                s[n][r4] = v;
                mx = fmaxf(mx, v);
            }
        }
        mx = fmaxf(mx, __shfl_xor(mx, 16));
        mx = fmaxf(mx, __shfl_xor(mx, 32));
        if (!__all(mx - m <= 8.0f)) {
            float newm = fmaxf(m, mx);
            float scl = __expf(m - newm);   // finite args (m init -1e30)
            m = newm;
            den *= scl;
            #pragma unroll
            for (int n2 = 0; n2 < 4; ++n2) {
                o[n2][0] *= scl; o[n2][1] *= scl;
                o[n2][2] *= scl; o[n2][3] *= scl;
            }
        }
        float ls = 0.f;
        #pragma unroll
        for (int n = 0; n < 4; ++n) {
            u16x4 pv4;
            #pragma unroll
            for (int r4 = 0; r4 < 4; ++r4) {
                float p = __expf(s[n][r4] - m);   // bounded by e^8
                ls += p;
                pv4[r4] = f2bf(p);
            }
            *(u16x4*)&sProb[qq][n * 16 + g4 * 4] = pv4;
        }
        ls += __shfl_xor(ls, 16);
        ls += __shfl_xor(ls, 32);
        den += ls;

        // PV
        __builtin_amdgcn_s_setprio(1);
        #pragma unroll
        for (int ki = 0; ki < 2; ++ki) {
            bf16x8 pa = *(const bf16x8*)&sProb[qq][ki * 32 + g4 * 8];
            #pragma unroll
            for (int n2 = 0; n2 < 4; ++n2) {
                int drow = n2 * 16 + ln15;
                int sl = (ki * 4 + g4) ^ (drow & 7);
                bf16x8 vf = *(const bf16x8*)&sV[0][bofs + drow * 64 + sl * 8];
                o[n2] = mfma16(vf, pa, o[n2]);
            }
        }
        __builtin_amdgcn_s_setprio(0);
    };

    // ---- main loop (r10/r14-proven): stage(c+1) -> compute(c) -> barrier ----
    for (int c2 = 0; c2 < 8; ++c2) {
        int c = c2 * 2;
        stage_chunk(c + 1, 1);
        compute_chunk(c, 0);
        __syncthreads();
        if (c2 < 7) stage_chunk(c + 2, 0);
        compute_chunk(c + 1, 1);
        __syncthreads();
    }

    const float inv = 1.0f / den;
    #pragma unroll
    for (int n2 = 0; n2 < 4; ++n2) {
        u16x4 hv;
        #pragma unroll
        for (int r4 = 0; r4 < 4; ++r4)
            hv[r4] = f2bf(o[n2][r4] * inv);
        size_t oidx = (tok0 + q0 + qq) * INNER_ + hd + n2 * 16 + g4 * 4;
        *(u16x4*)(atth + oidx) = hv;
    }
}

// ---------------------------------------------------------------------------
extern "C" void kernel_launch(void* const* d_in, const int* in_sizes, int n_in,
                              void* d_out, int out_size, void* d_ws, size_t ws_size,
                              hipStream_t stream)
{
    const float* x     = (const float*)d_in[0];
    const float* pos   = (const float*)d_in[1];
    const float* w_qkv = (const float*)d_in[2];
    const float* w_q   = (const float*)d_in[3];
    const float* b_q   = (const float*)d_in[4];
    const float* w_k   = (const float*)d_in[5];
    const float* b_k   = (const float*)d_in[6];
    const float* w_v   = (const float*)d_in[7];
    const float* b_v   = (const float*)d_in[8];
    const float* w_pos = (const float*)d_in[9];
    const float* bu    = (const float*)d_in[10];
    const float* bv    = (const float*)d_in[11];
    const float* w_ao  = (const float*)d_in[12];
    const float* b_ao  = (const float*)d_in[13];
    const float* w_o   = (const float*)d_in[14];
    const float* b_o   = (const float*)d_in[15];
    float* out = (float*)d_out;

    unsigned short* u = (unsigned short*)d_ws;
    const size_t SZ = (size_t)BT_ * INNER_;          // 4,194,304
    unsigned short* xh   = u;
    unsigned short* xl   = xh + SZ;                  // (unused)
    unsigned short* qu   = xl + SZ;
    unsigned short* qv   = qu + SZ;
    unsigned short* kb   = qv + SZ;
    unsigned short* vt   = kb + SZ;
    unsigned short* atth = vt + SZ;
    unsigned short* attl = atth + SZ;                // (unused)
    unsigned short* pb_base = attl + SZ;             // 512 slack + 2047*512
    unsigned short* pb0  = pb_base + 512;
    unsigned short* posh = pb_base + 1049600;
    unsigned short* posl = posh + 1049600;           // (unused)
    unsigned short* wqkvh = posl + 1049600;
    unsigned short* wqkvl = wqkvh + 786432;
    unsigned short* waoh  = wqkvl + 786432;
    unsigned short* waol  = waoh + 262144;
    unsigned short* w5    = waol + 262144;   // wq,wk,wv,wo,wp (h,l)
    unsigned short* wq_h = w5;              unsigned short* wq_l = w5 + 262144;
    unsigned short* wk_h = w5 + 2*262144;   unsigned short* wk_l = w5 + 3*262144;
    unsigned short* wv_h = w5 + 4*262144;   unsigned short* wv_l = w5 + 5*262144;
    unsigned short* wo_h = w5 + 6*262144;   unsigned short* wo_l = w5 + 7*262144;
    unsigned short* wp_h = w5 + 8*262144;   unsigned short* wp_l = w5 + 9*262144;
    unsigned short* wcat_h = w5 + 10*262144;         // [1536][512] eff q|k|v ^T
    unsigned short* wcat_l = wcat_h + 786432;
    unsigned short* woe_h  = wcat_l + 786432;
    unsigned short* woe_l  = woe_h + 262144;
    float* beff = (float*)(woe_l + 262144);

    dim3 blk(256);

    // 1) ALL preps in one dispatch (splits + weight transpose + bias_eff + pb0)
    PrepAll pa;
    pa.s[0] = x;     pa.h[0] = xh;    pa.l[0] = xl;    pa.n[0] = (long)SZ;          pa.wantl[0] = 0;
    pa.s[1] = w_qkv; pa.h[1] = wqkvh; pa.l[1] = wqkvl; pa.n[1] = 786432L;           pa.wantl[1] = 1;
    pa.s[2] = w_ao;  pa.h[2] = waoh;  pa.l[2] = waol;  pa.n[2] = 262144L;           pa.wantl[2] = 1;
    pa.s[3] = pos;   pa.h[3] = posh;  pa.l[3] = posl;  pa.n[3] = (long)PLEN_ * 512; pa.wantl[3] = 0;
    pa.w[0] = w_q;   pa.wh[0] = wq_h; pa.wl[0] = wq_l;
    pa.w[1] = w_k;   pa.wh[1] = wk_h; pa.wl[1] = wk_l;
    pa.w[2] = w_v;   pa.wh[2] = wv_h; pa.wl[2] = wv_l;
    pa.w[3] = w_o;   pa.wh[3] = wo_h; pa.wl[3] = wo_l;
    pa.w[4] = w_pos; pa.wh[4] = wp_h; pa.wl[4] = wp_l;
    pa.b_ao = b_ao; pa.w_o = w_o; pa.b_o = b_o; pa.be = beff; pa.pb_base = pb_base;
    prep_all<<<dim3(4096, 5), blk, 0, stream>>>(pa);

    // 2) transposed effective weights (64x64 tiles, 256 blocks)
    WeffT wt;
    wt.ah[0] = wq_h; wt.al[0] = wq_l;
    wt.ah[1] = wk_h; wt.al[1] = wk_l;
    wt.ah[2] = wv_h; wt.al[2] = wv_l;
    wt.ah[3] = wo_h; wt.al[3] = wo_l;
    wt.wh[0] = wqkvh;        wt.wl[0] = wqkvl;        wt.ldw[0] = 1536;
    wt.wh[1] = wqkvh + 512;  wt.wl[1] = wqkvl + 512;  wt.ldw[1] = 1536;
    wt.wh[2] = wqkvh + 1024; wt.wl[2] = wqkvl + 1024; wt.ldw[2] = 1536;
    wt.wh[3] = waoh;         wt.wl[3] = waol;         wt.ldw[3] = 512;
    wt.ch[0] = wcat_h;            wt.cl[0] = wcat_l;
    wt.ch[1] = wcat_h + 262144;   wt.cl[1] = wcat_l + 262144;
    wt.ch[2] = wcat_h + 2*262144; wt.cl[2] = wcat_l + 2*262144;
    wt.ch[3] = woe_h;             wt.cl[3] = woe_l;
    gemm_wefft<<<dim3(8, 8, 4), blk, 0, stream>>>(wt);

    // 3) merged q/k/v + pos projection (1D grid, XCD row-contiguous swizzle)
    gemm_qkvp<<<dim3(832), blk, 0, stream>>>(xh, wcat_h, wcat_l,
        posh, wp_h, wp_l,
        b_q, bu, bv, b_k, b_v, qu, qv, kb, vt, pb0);

    // 4) attention (single-bf16 output, XCD-aware block order, defer-max)
    attn_v16<<<1024, blk, 0, stream>>>(qu, qv, kb, vt, pb0, atth);

    // 5) output GEMM (2-term, 1D grid, XCD row-contiguous swizzle)
    gemm_out<<<dim3(512), blk, 0, stream>>>(atth, woe_h, woe_l, beff, out);
}

// Round 26
// 166.990 us; speedup vs baseline: 1.0043x; 1.0043x over previous
//
#include <hip/hip_runtime.h>
#include <hip/hip_bf16.h>
#include <math.h>

#define H_     8
#define DK_    64
#define INNER_ 512
#define B_     8
#define T_     1024
#define D_     512
#define PLEN_  2047
#define BT_    8192

typedef __attribute__((ext_vector_type(8))) short bf16x8;
typedef __attribute__((ext_vector_type(4))) float f32x4;
typedef __attribute__((ext_vector_type(4))) unsigned short u16x4;
typedef __attribute__((ext_vector_type(8))) unsigned short u16x8;

__device__ __forceinline__ unsigned short f2bf(float f) {
    unsigned u = __float_as_uint(f);
    u += 0x7fffu + ((u >> 16) & 1u);
    return (unsigned short)(u >> 16);
}
__device__ __forceinline__ float bf2f(unsigned short s) {
    return __uint_as_float(((unsigned)s) << 16);
}
__device__ __forceinline__ f32x4 mfma16(bf16x8 a, bf16x8 b, f32x4 c) {
    return __builtin_amdgcn_mfma_f32_16x16x32_bf16(a, b, c, 0, 0, 0);
}
__device__ __forceinline__ void gload16(const unsigned short* g, unsigned short* l) {
    __builtin_amdgcn_global_load_lds(
        (const __attribute__((address_space(1))) void*)g,
        (__attribute__((address_space(3))) void*)l,
        16, 0, 0);
}
#define BARRIER()  __builtin_amdgcn_s_barrier()
#define SCHEDBAR() __builtin_amdgcn_sched_barrier(0)
#define VMCNT(N)   asm volatile("s_waitcnt vmcnt(" #N ")" ::: "memory")

// QSCALE * log2(e): scores land in log2 domain -> exp2 softmax (no v_mul)
#define QSCALE 0.1803368801111204f
#define DEFER_THR 11.5424946f   // 8 * log2(e)

// ---------------------------------------------------------------------------
// prep_all: ONE dispatch for all preps.
// ---------------------------------------------------------------------------
struct PrepAll {
    const float* s[4];
    unsigned short* h[4];
    unsigned short* l[4];
    long n[4];
    int wantl[4];
    const float* w[5];
    unsigned short* wh[5];
    unsigned short* wl[5];
    const float* b_ao;
    const float* w_o;
    const float* b_o;
    float* be;
    unsigned short* pb_base;
};
__global__ __launch_bounds__(256) void prep_all(PrepAll a)
{
    const int y = blockIdx.y;
    const int t = threadIdx.x;
    if (y < 4) {
        long i4 = ((long)blockIdx.x * 256 + t) * 4;
        if (i4 >= a.n[y]) return;
        f32x4 v = *(const f32x4*)(a.s[y] + i4);
        u16x4 hh, ll;
        #pragma unroll
        for (int i = 0; i < 4; ++i) {
            unsigned short hb = f2bf(v[i]);
            hh[i] = hb;
            ll[i] = f2bf(v[i] - bf2f(hb));
        }
        *(u16x4*)(a.h[y] + i4) = hh;
        if (a.wantl[y]) *(u16x4*)(a.l[y] + i4) = ll;
        return;
    }
    const int x = blockIdx.x;
    if (x < 1280) {
        __shared__ float sW[32][36];
        const int z = x >> 8, idx = x & 255;
        const int n0 = (idx & 15) * 32, k0 = (idx >> 4) * 32;
        const float* w = a.w[z];
        unsigned short* wh = a.wh[z];
        unsigned short* wl = a.wl[z];
        {
            int kr = t >> 3, c4 = (t & 7) * 4;
            f32x4 v = *(const f32x4*)(w + (size_t)(k0 + kr) * 512 + n0 + c4);
            #pragma unroll
            for (int i = 0; i < 4; ++i) sW[kr][c4 + i] = v[i];
        }
        __syncthreads();
        {
            int nr = t >> 3, kc = (t & 7) * 4;
            u16x4 hv, lv;
            #pragma unroll
            for (int i = 0; i < 4; ++i) {
                float f = sW[kc + i][nr];
                unsigned short hb = f2bf(f);
                hv[i] = hb;
                lv[i] = f2bf(f - bf2f(hb));
            }
            *(u16x4*)(wh + (size_t)(n0 + nr) * 512 + k0 + kc) = hv;
            *(u16x4*)(wl + (size_t)(n0 + nr) * 512 + k0 + kc) = lv;
        }
        return;
    }
    if (x < 1282) {
        int n = (x - 1280) * 256 + t;
        float s = a.b_o[n];
        for (int j = 0; j < 512; ++j) s += a.b_ao[j] * a.w_o[(size_t)j * 512 + n];
        a.be[n] = s;
    } else if (x == 1282) {
        ((unsigned int*)a.pb_base)[t] = 0u;
    }
}

// ---------------------------------------------------------------------------
// gemm_core: counted-vmcnt double-barrier pipeline (r11/r14/r16/r17-proven).
// ---------------------------------------------------------------------------
template<int MF, bool ALO, int NJ>
__device__ __forceinline__ void gemm_core(
    f32x4 (&acc)[MF][NJ],
    const unsigned short* __restrict__ Ah_g,
    const unsigned short* __restrict__ Al_g, int lda,
    const unsigned short* __restrict__ Wh_g,
    const unsigned short* __restrict__ Wl_g, int ldw,
    int M, int row0, int col0,
    unsigned short* sAh, unsigned short* sAl,
    unsigned short* sWh, unsigned short* sWl)
{
    const int t = threadIdx.x;
    const int lane = t & 63, w = t >> 6;
    const int wm = w >> 1, wn = w & 1;
    const int ln15 = lane & 15, g4 = lane >> 4;
    const int ASZ = MF * 32 * 32;
    const int WSZ = NJ * 32 * 32;
    constexpr int NLD = (MF / 2) * (ALO ? 2 : 1) + (NJ / 2) * 2;

    auto stage = [&](int kt, int buf) {
        #pragma unroll
        for (int l = 0; l < MF / 2; ++l) {
            int e = l * 256 + w * 64 + lane;
            int row = e >> 2, slot = e & 3;
            int ss = slot ^ (row & 3);
            int gr = row0 + row;
            if (gr > M - 1) gr = M - 1;
            size_t ga = (size_t)gr * lda + kt * 32 + ss * 8;
            gload16(Ah_g + ga, sAh + buf * ASZ + (l * 256 + w * 64) * 8);
            if constexpr (ALO)
                gload16(Al_g + ga, sAl + buf * ASZ + (l * 256 + w * 64) * 8);
        }
        #pragma unroll
        for (int l = 0; l < NJ / 2; ++l) {
            int e = l * 256 + w * 64 + lane;
            int row = e >> 2, slot = e & 3;
            int ss = slot ^ (row & 3);
            size_t gw = (size_t)(col0 + row) * ldw + kt * 32 + ss * 8;
            gload16(Wh_g + gw, sWh + buf * WSZ + (l * 256 + w * 64) * 8);
            gload16(Wl_g + gw, sWl + buf * WSZ + (l * 256 + w * 64) * 8);
        }
    };
    auto comp = [&](int buf) {
        bf16x8 fah[MF], fal[MF], fwh[NJ], fwl[NJ];
        #pragma unroll
        for (int i = 0; i < MF; ++i) {
            int ar = wm * (MF * 16) + i * 16 + ln15;
            int sa = (g4 ^ (ar & 3)) * 8;
            fah[i] = *(const bf16x8*)&sAh[buf * ASZ + ar * 32 + sa];
            if constexpr (ALO)
                fal[i] = *(const bf16x8*)&sAl[buf * ASZ + ar * 32 + sa];
        }
        #pragma unroll
        for (int j = 0; j < NJ; ++j) {
            int wr = wn * (NJ * 16) + j * 16 + ln15;
            int sw = (g4 ^ (wr & 3)) * 8;
            fwh[j] = *(const bf16x8*)&sWh[buf * WSZ + wr * 32 + sw];
            fwl[j] = *(const bf16x8*)&sWl[buf * WSZ + wr * 32 + sw];
        }
        __builtin_amdgcn_s_setprio(1);
        #pragma unroll
        for (int mi = 0; mi < MF; ++mi)
            #pragma unroll
            for (int ni = 0; ni < NJ; ++ni) {
                acc[mi][ni] = mfma16(fah[mi], fwh[ni], acc[mi][ni]);
                acc[mi][ni] = mfma16(fah[mi], fwl[ni], acc[mi][ni]);
                if constexpr (ALO)
                    acc[mi][ni] = mfma16(fal[mi], fwh[ni], acc[mi][ni]);
            }
        __builtin_amdgcn_s_setprio(0);
    };

    stage(0, 0);
    for (int k2 = 0; k2 < 8; ++k2) {
        BARRIER();
        stage(2 * k2 + 1, 1);
        if constexpr (NLD == 6) { VMCNT(6); }
        else if constexpr (NLD == 5) { VMCNT(5); }
        else if constexpr (NLD == 4) { VMCNT(4); }
        else { VMCNT(8); }
        BARRIER(); SCHEDBAR();
        comp(0);
        BARRIER();
        if (k2 < 7) {
            stage(2 * k2 + 2, 0);
            if constexpr (NLD == 6) { VMCNT(6); }
            else if constexpr (NLD == 5) { VMCNT(5); }
            else if constexpr (NLD == 4) { VMCNT(4); }
            else { VMCNT(8); }
        } else {
            VMCNT(0);
        }
        BARRIER(); SCHEDBAR();
        comp(1);
    }
}

#define GEMM_LDS3(MF, NJ) \
    __shared__ __align__(16) unsigned short sAh[2][MF * 32 * 32]; \
    __shared__ __align__(16) unsigned short sAl[2][MF * 32 * 32]; \
    __shared__ __align__(16) unsigned short sWh[2][NJ * 32 * 32]; \
    __shared__ __align__(16) unsigned short sWl[2][NJ * 32 * 32];
#define GEMM_LDS2(MF, NJ) \
    __shared__ __align__(16) unsigned short sAh[2][MF * 32 * 32]; \
    __shared__ __align__(16) unsigned short sWh[2][NJ * 32 * 32]; \
    __shared__ __align__(16) unsigned short sWl[2][NJ * 32 * 32];

// ---- merged QKV + POS projection GEMM; 1D grid 832 = 8 XCDs x (8 rows x 13
// cols): XCD-contiguous row blocks make each A panel L2-exclusive ----
__global__ __launch_bounds__(256, 3) void gemm_qkvp(
    const unsigned short* __restrict__ Ah_g,
    const unsigned short* __restrict__ Wh_g,
    const unsigned short* __restrict__ Wl_g,
    const unsigned short* __restrict__ posh,
    const unsigned short* __restrict__ wp_h,
    const unsigned short* __restrict__ wp_l,
    const float* __restrict__ b_q, const float* __restrict__ bu,
    const float* __restrict__ bv, const float* __restrict__ b_k,
    const float* __restrict__ b_v,
    unsigned short* __restrict__ qu, unsigned short* __restrict__ qv,
    unsigned short* __restrict__ kb, unsigned short* __restrict__ vt,
    unsigned short* __restrict__ pb0)
{
    GEMM_LDS2(4, 4)
    f32x4 acc[4][4];
    #pragma unroll
    for (int i = 0; i < 4; ++i)
        #pragma unroll
        for (int j = 0; j < 4; ++j) acc[i][j] = (f32x4){0.f, 0.f, 0.f, 0.f};

    const int lin = blockIdx.x;                 // 0..831
    const int wgid = (lin & 7) * 104 + (lin >> 3);   // bijective: 832 = 8*104
    const int bx = wgid % 13, by = wgid / 13;
    const bool isPos = (bx == 12);
    int row0, col0, M;
    const unsigned short *Ag, *Whg, *Wlg;
    if (isPos) {
        row0 = (by >> 2) * 128; col0 = (by & 3) * 128;
        Ag = posh; Whg = wp_h; Wlg = wp_l; M = PLEN_;
    } else {
        row0 = by * 128; col0 = bx * 128;
        Ag = Ah_g; Whg = Wh_g; Wlg = Wl_g; M = BT_;
    }
    gemm_core<4, false, 4>(acc, Ag, nullptr, 512, Whg, Wlg, 512, M, row0, col0,
                           &sAh[0][0], &sAh[0][0], &sWh[0][0], &sWl[0][0]);

    const int t = threadIdx.x;
    const int lane = t & 63, w = t >> 6;
    const int wm = w >> 1, wn = w & 1;
    const int ln15 = lane & 15, g4 = lane >> 4;

    if (isPos) {
        #pragma unroll
        for (int mi = 0; mi < 4; ++mi)
            #pragma unroll
            for (int r4 = 0; r4 < 4; ++r4) {
                int gr = row0 + wm * 64 + mi * 16 + g4 * 4 + r4;
                if (gr >= PLEN_) continue;
                #pragma unroll
                for (int ni = 0; ni < 4; ++ni) {
                    int gc = col0 + wn * 64 + ni * 16 + ln15;
                    pb0[(size_t)gr * 512 + gc] = f2bf(acc[mi][ni][r4]);
                }
            }
        return;
    }

    const int grp = col0 >> 9;   // 0=q, 1=k, 2=v (block-uniform)
    if (grp == 2) {
        #pragma unroll
        for (int mi = 0; mi < 4; ++mi) {
            int gr0 = row0 + wm * 64 + mi * 16 + g4 * 4;
            int bb = gr0 >> 10, t0 = gr0 & 1023;
            #pragma unroll
            for (int ni = 0; ni < 4; ++ni) {
                int gcl = (col0 & 511) + wn * 64 + ni * 16 + ln15;
                float bias = b_v[gcl];
                u16x4 vv;
                #pragma unroll
                for (int r4 = 0; r4 < 4; ++r4) vv[r4] = f2bf(acc[mi][ni][r4] + bias);
                *(u16x4*)(vt + ((size_t)(bb * 512 + gcl)) * 1024 + t0) = vv;
            }
        }
    } else {
        #pragma unroll
        for (int mi = 0; mi < 4; ++mi)
            #pragma unroll
            for (int r4 = 0; r4 < 4; ++r4) {
                int gr = row0 + wm * 64 + mi * 16 + g4 * 4 + r4;
                #pragma unroll
                for (int ni = 0; ni < 4; ++ni) {
                    int gcl = (col0 & 511) + wn * 64 + ni * 16 + ln15;
                    float a = acc[mi][ni][r4];
                    if (grp == 0) {
                        float base = a + b_q[gcl];
                        qu[(size_t)gr * 512 + gcl] = f2bf((base + bu[gcl]) * QSCALE);
                        qv[(size_t)gr * 512 + gcl] = f2bf((base + bv[gcl]) * QSCALE);
                    } else {
                        kb[(size_t)gr * 512 + gcl] = f2bf(a + b_k[gcl]);
                    }
                }
            }
    }
}

// ---- transposed effective-weight GEMMs: 64x64 tiles (256 blocks) ----
struct WeffT {
    const unsigned short* ah[4];
    const unsigned short* al[4];
    const unsigned short* wh[4];
    const unsigned short* wl[4];
    int ldw[4];
    unsigned short* ch[4];
    unsigned short* cl[4];
};
__global__ __launch_bounds__(256, 3) void gemm_wefft(WeffT a)
{
    GEMM_LDS3(2, 2)
    const int z = blockIdx.z;
    f32x4 acc[2][2];
    #pragma unroll
    for (int i = 0; i < 2; ++i)
        #pragma unroll
        for (int j = 0; j < 2; ++j) acc[i][j] = (f32x4){0.f, 0.f, 0.f, 0.f};
    const int row0 = blockIdx.y * 64, col0 = blockIdx.x * 64;
    gemm_core<2, true, 2>(acc, a.ah[z], a.al[z], 512, a.wh[z], a.wl[z], a.ldw[z],
                          512, row0, col0,
                          &sAh[0][0], &sAl[0][0], &sWh[0][0], &sWl[0][0]);

    const int t = threadIdx.x;
    const int lane = t & 63, w = t >> 6;
    const int wm = w >> 1, wn = w & 1;
    const int ln15 = lane & 15, g4 = lane >> 4;
    unsigned short* Ch = a.ch[z];
    unsigned short* Cl = a.cl[z];
    #pragma unroll
    for (int mi = 0; mi < 2; ++mi)
        #pragma unroll
        for (int r4 = 0; r4 < 4; ++r4) {
            int gr = row0 + wm * 32 + mi * 16 + g4 * 4 + r4;
            #pragma unroll
            for (int ni = 0; ni < 2; ++ni) {
                int gc = col0 + wn * 32 + ni * 16 + ln15;
                float v = acc[mi][ni][r4];
                unsigned short hb = f2bf(v);
                Ch[(size_t)gr * 512 + gc] = hb;
                Cl[(size_t)gr * 512 + gc] = f2bf(v - bf2f(hb));
            }
        }
}

// ---- output GEMM: 64x128 tiles, 2-term; 1D grid 512 = 8 XCDs x (16r x 4c) ----
__global__ __launch_bounds__(256, 3) void gemm_out(
    const unsigned short* __restrict__ Ah_g,
    const unsigned short* __restrict__ Wh_g,
    const unsigned short* __restrict__ Wl_g,
    const float* __restrict__ beff, float* __restrict__ C)
{
    GEMM_LDS2(2, 4)
    f32x4 acc[2][4];
    #pragma unroll
    for (int i = 0; i < 2; ++i)
        #pragma unroll
        for (int j = 0; j < 4; ++j) acc[i][j] = (f32x4){0.f, 0.f, 0.f, 0.f};
    const int lin = blockIdx.x;                 // 0..511
    const int wgid = (lin & 7) * 64 + (lin >> 3);    // bijective: 512 = 8*64
    const int row0 = (wgid >> 2) * 64, col0 = (wgid & 3) * 128;
    gemm_core<2, false, 4>(acc, Ah_g, nullptr, 512, Wh_g, Wl_g, 512, BT_, row0, col0,
                           &sAh[0][0], &sAh[0][0], &sWh[0][0], &sWl[0][0]);

    const int t = threadIdx.x;
    const int lane = t & 63, w = t >> 6;
    const int wm = w >> 1, wn = w & 1;
    const int ln15 = lane & 15, g4 = lane >> 4;
    #pragma unroll
    for (int mi = 0; mi < 2; ++mi)
        #pragma unroll
        for (int r4 = 0; r4 < 4; ++r4) {
            int gr = row0 + wm * 32 + mi * 16 + g4 * 4 + r4;
            #pragma unroll
            for (int ni = 0; ni < 4; ++ni) {
                int gc = col0 + wn * 64 + ni * 16 + ln15;
                C[(size_t)gr * 512 + gc] = acc[mi][ni][r4] + beff[gc];
            }
        }
}

// ---------------------------------------------------------------------------
// attn_v17: attn_v16 + exp2-domain softmax (log2e folded into qu/qv by
// gemm_qkvp; v_exp_f32 computes 2^x natively -> drops 17 v_mul per chunk).
// Defer threshold 8*log2e keeps the same e^8 P bound.
// ---------------------------------------------------------------------------
__global__ __launch_bounds__(256, 2) void attn_v17(
    const unsigned short* __restrict__ qu_g,
    const unsigned short* __restrict__ qv_g,
    const unsigned short* __restrict__ kb_g,
    const unsigned short* __restrict__ vt_g,
    const unsigned short* __restrict__ pb_g,   // p=0 (zeroed 512-slack before)
    unsigned short* __restrict__ atth)
{
    __shared__ __align__(16) unsigned short sK[2][64 * 64];
    __shared__ __align__(16) unsigned short sP[2][64 * 64];
    __shared__ __align__(16) unsigned short sV[2][64 * 64];   // [d][token]
    __shared__ __align__(16) unsigned short ringb[64][132];   // rotated bf16 ring
    __shared__ __align__(16) unsigned short sProb[64][72];    // [q][k]

    const int t = threadIdx.x;
    const int lane = t & 63, w = t >> 6;
    const int ln15 = lane & 15, g4 = lane >> 4;

    const int wg = blockIdx.x;
    const int idx = (wg & 7) * 128 + (wg >> 3);   // XCD-aware (r18-proven)
    const int q0 = (idx & 15) * 64;
    const int bh = idx >> 4;
    const int h = bh & 7, b = bh >> 3;
    const size_t tok0 = (size_t)b * T_;
    const int hd = h * DK_;
    const int qq = w * 16 + ln15;

    auto stage_chunk = [&](int c, int buf) {
        #pragma unroll
        for (int l = 0; l < 2; ++l) {
            int e = l * 256 + w * 64 + lane;
            int row = e >> 3, slot = e & 7;
            int sl = slot ^ (row & 7);
            int lofs = buf * 4096 + (l * 256 + w * 64) * 8;
            gload16(kb_g + (tok0 + c * 64 + row) * INNER_ + hd + sl * 8, &sK[0][lofs]);
            gload16(vt_g + ((size_t)(b * H_ + h) * DK_ + row) * T_ + c * 64 + sl * 8, &sV[0][lofs]);
            long p = (long)(c * 64 - q0 + 1023 + row);
            gload16(pb_g + p * INNER_ + hd + sl * 8, &sP[0][lofs]);
        }
    };

    // ---- stage Qu -> sK[0], Qv -> sP[0]; pull fragments ----
    #pragma unroll
    for (int l = 0; l < 2; ++l) {
        int e = l * 256 + w * 64 + lane;
        int row = e >> 3, slot = e & 7;
        int sl = slot ^ (row & 7);
        size_t src = (tok0 + q0 + row) * INNER_ + hd + sl * 8;
        gload16(qu_g + src, &sK[0][(l * 256 + w * 64) * 8]);
        gload16(qv_g + src, &sP[0][(l * 256 + w * 64) * 8]);
    }
    __syncthreads();
    bf16x8 fqu[2], fqv[2];
    #pragma unroll
    for (int ki = 0; ki < 2; ++ki) {
        int sl = (ki * 4 + g4) ^ (qq & 7);
        fqu[ki] = *(const bf16x8*)&sK[0][qq * 64 + sl * 8];
        fqv[ki] = *(const bf16x8*)&sP[0][qq * 64 + sl * 8];
    }
    __syncthreads();   // frag ds_reads drained before buffers overwritten

    // ---- stage prologue-P window -> sP[1] AND chunk0 -> buf0 ----
    #pragma unroll
    for (int l = 0; l < 2; ++l) {
        int e = l * 256 + w * 64 + lane;
        int row = e >> 3, slot = e & 7;
        int sl = slot ^ (row & 7);
        long p = (long)(959 - q0 + row);
        gload16(pb_g + p * INNER_ + hd + sl * 8, &sP[0][4096 + (l * 256 + w * 64) * 8]);
    }
    stage_chunk(0, 0);
    __syncthreads();

    // ---- ring prologue (rotated by qq) ----
    #pragma unroll
    for (int n = 0; n < 4; ++n) {
        f32x4 bdv = {0.f, 0.f, 0.f, 0.f};
        #pragma unroll
        for (int ki = 0; ki < 2; ++ki) {
            int prow = n * 16 + ln15;
            int sl = (ki * 4 + g4) ^ (prow & 7);
            bf16x8 pf = *(const bf16x8*)&sP[0][4096 + prow * 64 + sl * 8];
            bdv = mfma16(pf, fqv[ki], bdv);
        }
        #pragma unroll
        for (int r4 = 0; r4 < 4; ++r4)
            ringb[qq][(n * 16 + g4 * 4 + r4 + qq) & 127] = f2bf(bdv[r4]);
    }
    __syncthreads();   // sP[1] free for chunk-1 prefetch

    float m = -1e30f, den = 0.f;
    f32x4 o[4];
    #pragma unroll
    for (int i = 0; i < 4; ++i) o[i] = (f32x4){0.f, 0.f, 0.f, 0.f};

    auto compute_chunk = [&](int c, int buf) {
        const int bofs = buf * 4096;
        f32x4 sc[4], bd[4];
        #pragma unroll
        for (int n = 0; n < 4; ++n) {
            sc[n] = (f32x4){0.f, 0.f, 0.f, 0.f};
            bd[n] = (f32x4){0.f, 0.f, 0.f, 0.f};
        }
        __builtin_amdgcn_s_setprio(1);
        #pragma unroll
        for (int ki = 0; ki < 2; ++ki)
            #pragma unroll
            for (int n = 0; n < 4; ++n) {
                int krow = n * 16 + ln15;
                int sl = (ki * 4 + g4) ^ (krow & 7);
                bf16x8 kf = *(const bf16x8*)&sK[0][bofs + krow * 64 + sl * 8];
                sc[n] = mfma16(kf, fqu[ki], sc[n]);
                bf16x8 pf = *(const bf16x8*)&sP[0][bofs + krow * 64 + sl * 8];
                bd[n] = mfma16(pf, fqv[ki], bd[n]);
            }
        __builtin_amdgcn_s_setprio(0);

        // ring write (rotated; f2bf)
        const int pbase = (c & 1) ? 0 : 64;
        #pragma unroll
        for (int n = 0; n < 4; ++n)
            #pragma unroll
            for (int r4 = 0; r4 < 4; ++r4)
                ringb[qq][(pbase + n * 16 + g4 * 4 + r4 + qq) & 127] = f2bf(bd[n][r4]);

        // scores + online softmax (log2 domain; T13 defer-max)
        float s[4][4];
        float mx = -1e30f;
        #pragma unroll
        for (int n = 0; n < 4; ++n) {
            const int st2 = (c * 64 + 64 + n * 16 + g4 * 4) & 127;
            u16x4 rv = *(const u16x4*)&ringb[qq][st2];
            #pragma unroll
            for (int r4 = 0; r4 < 4; ++r4) {
                float v = sc[n][r4] + bf2f(rv[r4]);
                s[n][r4] = v;
                mx = fmaxf(mx, v);
            }
        }
        mx = fmaxf(mx, __shfl_xor(mx, 16));
        mx = fmaxf(mx, __shfl_xor(mx, 32));
        if (!__all(mx - m <= DEFER_THR)) {
            float newm = fmaxf(m, mx);
            float scl = __builtin_amdgcn_exp2f(m - newm);   // finite args
            m = newm;
            den *= scl;
            #pragma unroll
            for (int n2 = 0; n2 < 4; ++n2) {
                o[n2][0] *= scl; o[n2][1] *= scl;
                o[n2][2] *= scl; o[n2][3] *= scl;
            }
        }
        float ls = 0.f;
        #pragma unroll
        for (int n = 0; n < 4; ++n) {
            u16x4 pv4;
            #pragma unroll
            for (int r4 = 0; r4 < 4; ++r4) {
                float p = __builtin_amdgcn_exp2f(s[n][r4] - m);  // <= 2^THR = e^8
                ls += p;
                pv4[r4] = f2bf(p);
            }
            *(u16x4*)&sProb[qq][n * 16 + g4 * 4] = pv4;
        }
        ls += __shfl_xor(ls, 16);
        ls += __shfl_xor(ls, 32);
        den += ls;

        // PV
        __builtin_amdgcn_s_setprio(1);
        #pragma unroll
        for (int ki = 0; ki < 2; ++ki) {
            bf16x8 pa = *(const bf16x8*)&sProb[qq][ki * 32 + g4 * 8];
            #pragma unroll
            for (int n2 = 0; n2 < 4; ++n2) {
                int drow = n2 * 16 + ln15;
                int sl = (ki * 4 + g4) ^ (drow & 7);
                bf16x8 vf = *(const bf16x8*)&sV[0][bofs + drow * 64 + sl * 8];
                o[n2] = mfma16(vf, pa, o[n2]);
            }
        }
        __builtin_amdgcn_s_setprio(0);
    };

    // ---- main loop (r10/r14-proven): stage(c+1) -> compute(c) -> barrier ----
    for (int c2 = 0; c2 < 8; ++c2) {
        int c = c2 * 2;
        stage_chunk(c + 1, 1);
        compute_chunk(c, 0);
        __syncthreads();
        if (c2 < 7) stage_chunk(c + 2, 0);
        compute_chunk(c + 1, 1);
        __syncthreads();
    }

    const float inv = 1.0f / den;
    #pragma unroll
    for (int n2 = 0; n2 < 4; ++n2) {
        u16x4 hv;
        #pragma unroll
        for (int r4 = 0; r4 < 4; ++r4)
            hv[r4] = f2bf(o[n2][r4] * inv);
        size_t oidx = (tok0 + q0 + qq) * INNER_ + hd + n2 * 16 + g4 * 4;
        *(u16x4*)(atth + oidx) = hv;
    }
}

// ---------------------------------------------------------------------------
extern "C" void kernel_launch(void* const* d_in, const int* in_sizes, int n_in,
                              void* d_out, int out_size, void* d_ws, size_t ws_size,
                              hipStream_t stream)
{
    const float* x     = (const float*)d_in[0];
    const float* pos   = (const float*)d_in[1];
    const float* w_qkv = (const float*)d_in[2];
    const float* w_q   = (const float*)d_in[3];
    const float* b_q   = (const float*)d_in[4];
    const float* w_k   = (const float*)d_in[5];
    const float* b_k   = (const float*)d_in[6];
    const float* w_v   = (const float*)d_in[7];
    const float* b_v   = (const float*)d_in[8];
    const float* w_pos = (const float*)d_in[9];
    const float* bu    = (const float*)d_in[10];
    const float* bv    = (const float*)d_in[11];
    const float* w_ao  = (const float*)d_in[12];
    const float* b_ao  = (const float*)d_in[13];
    const float* w_o   = (const float*)d_in[14];
    const float* b_o   = (const float*)d_in[15];
    float* out = (float*)d_out;

    unsigned short* u = (unsigned short*)d_ws;
    const size_t SZ = (size_t)BT_ * INNER_;          // 4,194,304
    unsigned short* xh   = u;
    unsigned short* xl   = xh + SZ;                  // (unused)
    unsigned short* qu   = xl + SZ;
    unsigned short* qv   = qu + SZ;
    unsigned short* kb   = qv + SZ;
    unsigned short* vt   = kb + SZ;
    unsigned short* atth = vt + SZ;
    unsigned short* attl = atth + SZ;                // (unused)
    unsigned short* pb_base = attl + SZ;             // 512 slack + 2047*512
    unsigned short* pb0  = pb_base + 512;
    unsigned short* posh = pb_base + 1049600;
    unsigned short* posl = posh + 1049600;           // (unused)
    unsigned short* wqkvh = posl + 1049600;
    unsigned short* wqkvl = wqkvh + 786432;
    unsigned short* waoh  = wqkvl + 786432;
    unsigned short* waol  = waoh + 262144;
    unsigned short* w5    = waol + 262144;   // wq,wk,wv,wo,wp (h,l)
    unsigned short* wq_h = w5;              unsigned short* wq_l = w5 + 262144;
    unsigned short* wk_h = w5 + 2*262144;   unsigned short* wk_l = w5 + 3*262144;
    unsigned short* wv_h = w5 + 4*262144;   unsigned short* wv_l = w5 + 5*262144;
    unsigned short* wo_h = w5 + 6*262144;   unsigned short* wo_l = w5 + 7*262144;
    unsigned short* wp_h = w5 + 8*262144;   unsigned short* wp_l = w5 + 9*262144;
    unsigned short* wcat_h = w5 + 10*262144;         // [1536][512] eff q|k|v ^T
    unsigned short* wcat_l = wcat_h + 786432;
    unsigned short* woe_h  = wcat_l + 786432;
    unsigned short* woe_l  = woe_h + 262144;
    float* beff = (float*)(woe_l + 262144);

    dim3 blk(256);

    // 1) ALL preps in one dispatch (splits + weight transpose + bias_eff + pb0)
    PrepAll pa;
    pa.s[0] = x;     pa.h[0] = xh;    pa.l[0] = xl;    pa.n[0] = (long)SZ;          pa.wantl[0] = 0;
    pa.s[1] = w_qkv; pa.h[1] = wqkvh; pa.l[1] = wqkvl; pa.n[1] = 786432L;           pa.wantl[1] = 1;
    pa.s[2] = w_ao;  pa.h[2] = waoh;  pa.l[2] = waol;  pa.n[2] = 262144L;           pa.wantl[2] = 1;
    pa.s[3] = pos;   pa.h[3] = posh;  pa.l[3] = posl;  pa.n[3] = (long)PLEN_ * 512; pa.wantl[3] = 0;
    pa.w[0] = w_q;   pa.wh[0] = wq_h; pa.wl[0] = wq_l;
    pa.w[1] = w_k;   pa.wh[1] = wk_h; pa.wl[1] = wk_l;
    pa.w[2] = w_v;   pa.wh[2] = wv_h; pa.wl[2] = wv_l;
    pa.w[3] = w_o;   pa.wh[3] = wo_h; pa.wl[3] = wo_l;
    pa.w[4] = w_pos; pa.wh[4] = wp_h; pa.wl[4] = wp_l;
    pa.b_ao = b_ao; pa.w_o = w_o; pa.b_o = b_o; pa.be = beff; pa.pb_base = pb_base;
    prep_all<<<dim3(4096, 5), blk, 0, stream>>>(pa);

    // 2) transposed effective weights (64x64 tiles, 256 blocks)
    WeffT wt;
    wt.ah[0] = wq_h; wt.al[0] = wq_l;
    wt.ah[1] = wk_h; wt.al[1] = wk_l;
    wt.ah[2] = wv_h; wt.al[2] = wv_l;
    wt.ah[3] = wo_h; wt.al[3] = wo_l;
    wt.wh[0] = wqkvh;        wt.wl[0] = wqkvl;        wt.ldw[0] = 1536;
    wt.wh[1] = wqkvh + 512;  wt.wl[1] = wqkvl + 512;  wt.ldw[1] = 1536;
    wt.wh[2] = wqkvh + 1024; wt.wl[2] = wqkvl + 1024; wt.ldw[2] = 1536;
    wt.wh[3] = waoh;         wt.wl[3] = waol;         wt.ldw[3] = 512;
    wt.ch[0] = wcat_h;            wt.cl[0] = wcat_l;
    wt.ch[1] = wcat_h + 262144;   wt.cl[1] = wcat_l + 262144;
    wt.ch[2] = wcat_h + 2*262144; wt.cl[2] = wcat_l + 2*262144;
    wt.ch[3] = woe_h;             wt.cl[3] = woe_l;
    gemm_wefft<<<dim3(8, 8, 4), blk, 0, stream>>>(wt);

    // 3) merged q/k/v + pos projection (1D grid, XCD row-contiguous swizzle)
    gemm_qkvp<<<dim3(832), blk, 0, stream>>>(xh, wcat_h, wcat_l,
        posh, wp_h, wp_l,
        b_q, bu, bv, b_k, b_v, qu, qv, kb, vt, pb0);

    // 4) attention (exp2-domain softmax, XCD-aware block order, defer-max)
    attn_v17<<<1024, blk, 0, stream>>>(qu, qv, kb, vt, pb0, atth);

    // 5) output GEMM (2-term, 1D grid, XCD row-contiguous swizzle)
    gemm_out<<<dim3(512), blk, 0, stream>>>(atth, woe_h, woe_l, beff, out);
}

// Round 27
// 163.967 us; speedup vs baseline: 1.0228x; 1.0184x over previous
//
#include <hip/hip_runtime.h>
#include <hip/hip_bf16.h>
#include <math.h>

#define H_     8
#define DK_    64
#define INNER_ 512
#define B_     8
#define T_     1024
#define D_     512
#define PLEN_  2047
#define BT_    8192

typedef __attribute__((ext_vector_type(8))) short bf16x8;
typedef __attribute__((ext_vector_type(4))) float f32x4;
typedef __attribute__((ext_vector_type(4))) unsigned short u16x4;
typedef __attribute__((ext_vector_type(8))) unsigned short u16x8;

__device__ __forceinline__ unsigned short f2bf(float f) {
    unsigned u = __float_as_uint(f);
    u += 0x7fffu + ((u >> 16) & 1u);
    return (unsigned short)(u >> 16);
}
__device__ __forceinline__ float bf2f(unsigned short s) {
    return __uint_as_float(((unsigned)s) << 16);
}
__device__ __forceinline__ f32x4 mfma16(bf16x8 a, bf16x8 b, f32x4 c) {
    return __builtin_amdgcn_mfma_f32_16x16x32_bf16(a, b, c, 0, 0, 0);
}
__device__ __forceinline__ void gload16(const unsigned short* g, unsigned short* l) {
    __builtin_amdgcn_global_load_lds(
        (const __attribute__((address_space(1))) void*)g,
        (__attribute__((address_space(3))) void*)l,
        16, 0, 0);
}
#define BARRIER()  __builtin_amdgcn_s_barrier()
#define SCHEDBAR() __builtin_amdgcn_sched_barrier(0)
#define VMCNT(N)   asm volatile("s_waitcnt vmcnt(" #N ")" ::: "memory")

// QSCALE * log2(e): scores land in log2 domain -> exp2 softmax (no v_mul)
#define QSCALE 0.1803368801111204f
#define DEFER_THR 11.5424946f   // 8 * log2(e)

// ---------------------------------------------------------------------------
// prep_all: ONE dispatch for all preps.
// ---------------------------------------------------------------------------
struct PrepAll {
    const float* s[4];
    unsigned short* h[4];
    unsigned short* l[4];
    long n[4];
    int wantl[4];
    const float* w[5];
    unsigned short* wh[5];
    unsigned short* wl[5];
    const float* b_ao;
    const float* w_o;
    const float* b_o;
    float* be;
    unsigned short* pb_base;
};
__global__ __launch_bounds__(256) void prep_all(PrepAll a)
{
    const int y = blockIdx.y;
    const int t = threadIdx.x;
    if (y < 4) {
        long i4 = ((long)blockIdx.x * 256 + t) * 4;
        if (i4 >= a.n[y]) return;
        f32x4 v = *(const f32x4*)(a.s[y] + i4);
        u16x4 hh, ll;
        #pragma unroll
        for (int i = 0; i < 4; ++i) {
            unsigned short hb = f2bf(v[i]);
            hh[i] = hb;
            ll[i] = f2bf(v[i] - bf2f(hb));
        }
        *(u16x4*)(a.h[y] + i4) = hh;
        if (a.wantl[y]) *(u16x4*)(a.l[y] + i4) = ll;
        return;
    }
    const int x = blockIdx.x;
    if (x < 1280) {
        __shared__ float sW[32][36];
        const int z = x >> 8, idx = x & 255;
        const int n0 = (idx & 15) * 32, k0 = (idx >> 4) * 32;
        const float* w = a.w[z];
        unsigned short* wh = a.wh[z];
        unsigned short* wl = a.wl[z];
        {
            int kr = t >> 3, c4 = (t & 7) * 4;
            f32x4 v = *(const f32x4*)(w + (size_t)(k0 + kr) * 512 + n0 + c4);
            #pragma unroll
            for (int i = 0; i < 4; ++i) sW[kr][c4 + i] = v[i];
        }
        __syncthreads();
        {
            int nr = t >> 3, kc = (t & 7) * 4;
            u16x4 hv, lv;
            #pragma unroll
            for (int i = 0; i < 4; ++i) {
                float f = sW[kc + i][nr];
                unsigned short hb = f2bf(f);
                hv[i] = hb;
                lv[i] = f2bf(f - bf2f(hb));
            }
            *(u16x4*)(wh + (size_t)(n0 + nr) * 512 + k0 + kc) = hv;
            *(u16x4*)(wl + (size_t)(n0 + nr) * 512 + k0 + kc) = lv;
        }
        return;
    }
    if (x < 1282) {
        int n = (x - 1280) * 256 + t;
        float s = a.b_o[n];
        for (int j = 0; j < 512; ++j) s += a.b_ao[j] * a.w_o[(size_t)j * 512 + n];
        a.be[n] = s;
    } else if (x == 1282) {
        ((unsigned int*)a.pb_base)[t] = 0u;
    }
}

// ---------------------------------------------------------------------------
// gemm_core: counted-vmcnt double-barrier pipeline (r11/r14/r16/r17-proven).
// ---------------------------------------------------------------------------
template<int MF, bool ALO, int NJ>
__device__ __forceinline__ void gemm_core(
    f32x4 (&acc)[MF][NJ],
    const unsigned short* __restrict__ Ah_g,
    const unsigned short* __restrict__ Al_g, int lda,
    const unsigned short* __restrict__ Wh_g,
    const unsigned short* __restrict__ Wl_g, int ldw,
    int M, int row0, int col0,
    unsigned short* sAh, unsigned short* sAl,
    unsigned short* sWh, unsigned short* sWl)
{
    const int t = threadIdx.x;
    const int lane = t & 63, w = t >> 6;
    const int wm = w >> 1, wn = w & 1;
    const int ln15 = lane & 15, g4 = lane >> 4;
    const int ASZ = MF * 32 * 32;
    const int WSZ = NJ * 32 * 32;
    constexpr int NLD = (MF / 2) * (ALO ? 2 : 1) + (NJ / 2) * 2;

    auto stage = [&](int kt, int buf) {
        #pragma unroll
        for (int l = 0; l < MF / 2; ++l) {
            int e = l * 256 + w * 64 + lane;
            int row = e >> 2, slot = e & 3;
            int ss = slot ^ (row & 3);
            int gr = row0 + row;
            if (gr > M - 1) gr = M - 1;
            size_t ga = (size_t)gr * lda + kt * 32 + ss * 8;
            gload16(Ah_g + ga, sAh + buf * ASZ + (l * 256 + w * 64) * 8);
            if constexpr (ALO)
                gload16(Al_g + ga, sAl + buf * ASZ + (l * 256 + w * 64) * 8);
        }
        #pragma unroll
        for (int l = 0; l < NJ / 2; ++l) {
            int e = l * 256 + w * 64 + lane;
            int row = e >> 2, slot = e & 3;
            int ss = slot ^ (row & 3);
            size_t gw = (size_t)(col0 + row) * ldw + kt * 32 + ss * 8;
            gload16(Wh_g + gw, sWh + buf * WSZ + (l * 256 + w * 64) * 8);
            gload16(Wl_g + gw, sWl + buf * WSZ + (l * 256 + w * 64) * 8);
        }
    };
    auto comp = [&](int buf) {
        bf16x8 fah[MF], fal[MF], fwh[NJ], fwl[NJ];
        #pragma unroll
        for (int i = 0; i < MF; ++i) {
            int ar = wm * (MF * 16) + i * 16 + ln15;
            int sa = (g4 ^ (ar & 3)) * 8;
            fah[i] = *(const bf16x8*)&sAh[buf * ASZ + ar * 32 + sa];
            if constexpr (ALO)
                fal[i] = *(const bf16x8*)&sAl[buf * ASZ + ar * 32 + sa];
        }
        #pragma unroll
        for (int j = 0; j < NJ; ++j) {
            int wr = wn * (NJ * 16) + j * 16 + ln15;
            int sw = (g4 ^ (wr & 3)) * 8;
            fwh[j] = *(const bf16x8*)&sWh[buf * WSZ + wr * 32 + sw];
            fwl[j] = *(const bf16x8*)&sWl[buf * WSZ + wr * 32 + sw];
        }
        __builtin_amdgcn_s_setprio(1);
        #pragma unroll
        for (int mi = 0; mi < MF; ++mi)
            #pragma unroll
            for (int ni = 0; ni < NJ; ++ni) {
                acc[mi][ni] = mfma16(fah[mi], fwh[ni], acc[mi][ni]);
                acc[mi][ni] = mfma16(fah[mi], fwl[ni], acc[mi][ni]);
                if constexpr (ALO)
                    acc[mi][ni] = mfma16(fal[mi], fwh[ni], acc[mi][ni]);
            }
        __builtin_amdgcn_s_setprio(0);
    };

    stage(0, 0);
    for (int k2 = 0; k2 < 8; ++k2) {
        BARRIER();
        stage(2 * k2 + 1, 1);
        if constexpr (NLD == 6) { VMCNT(6); }
        else if constexpr (NLD == 5) { VMCNT(5); }
        else if constexpr (NLD == 4) { VMCNT(4); }
        else { VMCNT(8); }
        BARRIER(); SCHEDBAR();
        comp(0);
        BARRIER();
        if (k2 < 7) {
            stage(2 * k2 + 2, 0);
            if constexpr (NLD == 6) { VMCNT(6); }
            else if constexpr (NLD == 5) { VMCNT(5); }
            else if constexpr (NLD == 4) { VMCNT(4); }
            else { VMCNT(8); }
        } else {
            VMCNT(0);
        }
        BARRIER(); SCHEDBAR();
        comp(1);
    }
}

#define GEMM_LDS3(MF, NJ) \
    __shared__ __align__(16) unsigned short sAh[2][MF * 32 * 32]; \
    __shared__ __align__(16) unsigned short sAl[2][MF * 32 * 32]; \
    __shared__ __align__(16) unsigned short sWh[2][NJ * 32 * 32]; \
    __shared__ __align__(16) unsigned short sWl[2][NJ * 32 * 32];
#define GEMM_LDS2(MF, NJ) \
    __shared__ __align__(16) unsigned short sAh[2][MF * 32 * 32]; \
    __shared__ __align__(16) unsigned short sWh[2][NJ * 32 * 32]; \
    __shared__ __align__(16) unsigned short sWl[2][NJ * 32 * 32];

// ---- merged QKV + POS projection GEMM; 1D grid 832 = 8 XCDs x (8 rows x 13
// cols): XCD-contiguous row blocks make each A panel L2-exclusive ----
__global__ __launch_bounds__(256, 3) void gemm_qkvp(
    const unsigned short* __restrict__ Ah_g,
    const unsigned short* __restrict__ Wh_g,
    const unsigned short* __restrict__ Wl_g,
    const unsigned short* __restrict__ posh,
    const unsigned short* __restrict__ wp_h,
    const unsigned short* __restrict__ wp_l,
    const float* __restrict__ b_q, const float* __restrict__ bu,
    const float* __restrict__ bv, const float* __restrict__ b_k,
    const float* __restrict__ b_v,
    unsigned short* __restrict__ qu, unsigned short* __restrict__ qv,
    unsigned short* __restrict__ kb, unsigned short* __restrict__ vt,
    unsigned short* __restrict__ pb0)
{
    GEMM_LDS2(4, 4)
    f32x4 acc[4][4];
    #pragma unroll
    for (int i = 0; i < 4; ++i)
        #pragma unroll
        for (int j = 0; j < 4; ++j) acc[i][j] = (f32x4){0.f, 0.f, 0.f, 0.f};

    const int lin = blockIdx.x;                 // 0..831
    const int wgid = (lin & 7) * 104 + (lin >> 3);   // bijective: 832 = 8*104
    const int bx = wgid % 13, by = wgid / 13;
    const bool isPos = (bx == 12);
    int row0, col0, M;
    const unsigned short *Ag, *Whg, *Wlg;
    if (isPos) {
        row0 = (by >> 2) * 128; col0 = (by & 3) * 128;
        Ag = posh; Whg = wp_h; Wlg = wp_l; M = PLEN_;
    } else {
        row0 = by * 128; col0 = bx * 128;
        Ag = Ah_g; Whg = Wh_g; Wlg = Wl_g; M = BT_;
    }
    gemm_core<4, false, 4>(acc, Ag, nullptr, 512, Whg, Wlg, 512, M, row0, col0,
                           &sAh[0][0], &sAh[0][0], &sWh[0][0], &sWl[0][0]);

    const int t = threadIdx.x;
    const int lane = t & 63, w = t >> 6;
    const int wm = w >> 1, wn = w & 1;
    const int ln15 = lane & 15, g4 = lane >> 4;

    if (isPos) {
        #pragma unroll
        for (int mi = 0; mi < 4; ++mi)
            #pragma unroll
            for (int r4 = 0; r4 < 4; ++r4) {
                int gr = row0 + wm * 64 + mi * 16 + g4 * 4 + r4;
                if (gr >= PLEN_) continue;
                #pragma unroll
                for (int ni = 0; ni < 4; ++ni) {
                    int gc = col0 + wn * 64 + ni * 16 + ln15;
                    pb0[(size_t)gr * 512 + gc] = f2bf(acc[mi][ni][r4]);
                }
            }
        return;
    }

    const int grp = col0 >> 9;   // 0=q, 1=k, 2=v (block-uniform)
    if (grp == 2) {
        #pragma unroll
        for (int mi = 0; mi < 4; ++mi) {
            int gr0 = row0 + wm * 64 + mi * 16 + g4 * 4;
            int bb = gr0 >> 10, t0 = gr0 & 1023;
            #pragma unroll
            for (int ni = 0; ni < 4; ++ni) {
                int gcl = (col0 & 511) + wn * 64 + ni * 16 + ln15;
                float bias = b_v[gcl];
                u16x4 vv;
                #pragma unroll
                for (int r4 = 0; r4 < 4; ++r4) vv[r4] = f2bf(acc[mi][ni][r4] + bias);
                *(u16x4*)(vt + ((size_t)(bb * 512 + gcl)) * 1024 + t0) = vv;
            }
        }
    } else {
        #pragma unroll
        for (int mi = 0; mi < 4; ++mi)
            #pragma unroll
            for (int r4 = 0; r4 < 4; ++r4) {
                int gr = row0 + wm * 64 + mi * 16 + g4 * 4 + r4;
                #pragma unroll
                for (int ni = 0; ni < 4; ++ni) {
                    int gcl = (col0 & 511) + wn * 64 + ni * 16 + ln15;
                    float a = acc[mi][ni][r4];
                    if (grp == 0) {
                        float base = a + b_q[gcl];
                        qu[(size_t)gr * 512 + gcl] = f2bf((base + bu[gcl]) * QSCALE);
                        qv[(size_t)gr * 512 + gcl] = f2bf((base + bv[gcl]) * QSCALE);
                    } else {
                        kb[(size_t)gr * 512 + gcl] = f2bf(a + b_k[gcl]);
                    }
                }
            }
    }
}

// ---- transposed effective-weight GEMMs: 64x64 tiles (256 blocks) ----
struct WeffT {
    const unsigned short* ah[4];
    const unsigned short* al[4];
    const unsigned short* wh[4];
    const unsigned short* wl[4];
    int ldw[4];
    unsigned short* ch[4];
    unsigned short* cl[4];
};
__global__ __launch_bounds__(256, 3) void gemm_wefft(WeffT a)
{
    GEMM_LDS3(2, 2)
    const int z = blockIdx.z;
    f32x4 acc[2][2];
    #pragma unroll
    for (int i = 0; i < 2; ++i)
        #pragma unroll
        for (int j = 0; j < 2; ++j) acc[i][j] = (f32x4){0.f, 0.f, 0.f, 0.f};
    const int row0 = blockIdx.y * 64, col0 = blockIdx.x * 64;
    gemm_core<2, true, 2>(acc, a.ah[z], a.al[z], 512, a.wh[z], a.wl[z], a.ldw[z],
                          512, row0, col0,
                          &sAh[0][0], &sAl[0][0], &sWh[0][0], &sWl[0][0]);

    const int t = threadIdx.x;
    const int lane = t & 63, w = t >> 6;
    const int wm = w >> 1, wn = w & 1;
    const int ln15 = lane & 15, g4 = lane >> 4;
    unsigned short* Ch = a.ch[z];
    unsigned short* Cl = a.cl[z];
    #pragma unroll
    for (int mi = 0; mi < 2; ++mi)
        #pragma unroll
        for (int r4 = 0; r4 < 4; ++r4) {
            int gr = row0 + wm * 32 + mi * 16 + g4 * 4 + r4;
            #pragma unroll
            for (int ni = 0; ni < 2; ++ni) {
                int gc = col0 + wn * 32 + ni * 16 + ln15;
                float v = acc[mi][ni][r4];
                unsigned short hb = f2bf(v);
                Ch[(size_t)gr * 512 + gc] = hb;
                Cl[(size_t)gr * 512 + gc] = f2bf(v - bf2f(hb));
            }
        }
}

// ---- output GEMM: 64x128 tiles, 2-term; 1D grid 512 = 8 XCDs x (16r x 4c) ----
__global__ __launch_bounds__(256, 3) void gemm_out(
    const unsigned short* __restrict__ Ah_g,
    const unsigned short* __restrict__ Wh_g,
    const unsigned short* __restrict__ Wl_g,
    const float* __restrict__ beff, float* __restrict__ C)
{
    GEMM_LDS2(2, 4)
    f32x4 acc[2][4];
    #pragma unroll
    for (int i = 0; i < 2; ++i)
        #pragma unroll
        for (int j = 0; j < 4; ++j) acc[i][j] = (f32x4){0.f, 0.f, 0.f, 0.f};
    const int lin = blockIdx.x;                 // 0..511
    const int wgid = (lin & 7) * 64 + (lin >> 3);    // bijective: 512 = 8*64
    const int row0 = (wgid >> 2) * 64, col0 = (wgid & 3) * 128;
    gemm_core<2, false, 4>(acc, Ah_g, nullptr, 512, Wh_g, Wl_g, 512, BT_, row0, col0,
                           &sAh[0][0], &sAh[0][0], &sWh[0][0], &sWl[0][0]);

    const int t = threadIdx.x;
    const int lane = t & 63, w = t >> 6;
    const int wm = w >> 1, wn = w & 1;
    const int ln15 = lane & 15, g4 = lane >> 4;
    #pragma unroll
    for (int mi = 0; mi < 2; ++mi)
        #pragma unroll
        for (int r4 = 0; r4 < 4; ++r4) {
            int gr = row0 + wm * 32 + mi * 16 + g4 * 4 + r4;
            #pragma unroll
            for (int ni = 0; ni < 4; ++ni) {
                int gc = col0 + wn * 64 + ni * 16 + ln15;
                C[(size_t)gr * 512 + gc] = acc[mi][ni][r4] + beff[gc];
            }
        }
}

// ---------------------------------------------------------------------------
// attn_v18: attn_v17 + softmax cross-lane cuts: (a) tree-fmax (v_max3),
// (b) per-thread defer predicate (row-max shuffles only inside rare rescale
// branch — __all over per-thread maxes is equivalent), (c) per-thread den,
// reduced once in epilogue (scl is row-uniform so per-thread scaling is exact).
// ---------------------------------------------------------------------------
__global__ __launch_bounds__(256, 2) void attn_v18(
    const unsigned short* __restrict__ qu_g,
    const unsigned short* __restrict__ qv_g,
    const unsigned short* __restrict__ kb_g,
    const unsigned short* __restrict__ vt_g,
    const unsigned short* __restrict__ pb_g,   // p=0 (zeroed 512-slack before)
    unsigned short* __restrict__ atth)
{
    __shared__ __align__(16) unsigned short sK[2][64 * 64];
    __shared__ __align__(16) unsigned short sP[2][64 * 64];
    __shared__ __align__(16) unsigned short sV[2][64 * 64];   // [d][token]
    __shared__ __align__(16) unsigned short ringb[64][132];   // rotated bf16 ring
    __shared__ __align__(16) unsigned short sProb[64][72];    // [q][k]

    const int t = threadIdx.x;
    const int lane = t & 63, w = t >> 6;
    const int ln15 = lane & 15, g4 = lane >> 4;

    const int wg = blockIdx.x;
    const int idx = (wg & 7) * 128 + (wg >> 3);   // XCD-aware (r18-proven)
    const int q0 = (idx & 15) * 64;
    const int bh = idx >> 4;
    const int h = bh & 7, b = bh >> 3;
    const size_t tok0 = (size_t)b * T_;
    const int hd = h * DK_;
    const int qq = w * 16 + ln15;

    auto stage_chunk = [&](int c, int buf) {
        #pragma unroll
        for (int l = 0; l < 2; ++l) {
            int e = l * 256 + w * 64 + lane;
            int row = e >> 3, slot = e & 7;
            int sl = slot ^ (row & 7);
            int lofs = buf * 4096 + (l * 256 + w * 64) * 8;
            gload16(kb_g + (tok0 + c * 64 + row) * INNER_ + hd + sl * 8, &sK[0][lofs]);
            gload16(vt_g + ((size_t)(b * H_ + h) * DK_ + row) * T_ + c * 64 + sl * 8, &sV[0][lofs]);
            long p = (long)(c * 64 - q0 + 1023 + row);
            gload16(pb_g + p * INNER_ + hd + sl * 8, &sP[0][lofs]);
        }
    };

    // ---- stage Qu -> sK[0], Qv -> sP[0]; pull fragments ----
    #pragma unroll
    for (int l = 0; l < 2; ++l) {
        int e = l * 256 + w * 64 + lane;
        int row = e >> 3, slot = e & 7;
        int sl = slot ^ (row & 7);
        size_t src = (tok0 + q0 + row) * INNER_ + hd + sl * 8;
        gload16(qu_g + src, &sK[0][(l * 256 + w * 64) * 8]);
        gload16(qv_g + src, &sP[0][(l * 256 + w * 64) * 8]);
    }
    __syncthreads();
    bf16x8 fqu[2], fqv[2];
    #pragma unroll
    for (int ki = 0; ki < 2; ++ki) {
        int sl = (ki * 4 + g4) ^ (qq & 7);
        fqu[ki] = *(const bf16x8*)&sK[0][qq * 64 + sl * 8];
        fqv[ki] = *(const bf16x8*)&sP[0][qq * 64 + sl * 8];
    }
    __syncthreads();   // frag ds_reads drained before buffers overwritten

    // ---- stage prologue-P window -> sP[1] AND chunk0 -> buf0 ----
    #pragma unroll
    for (int l = 0; l < 2; ++l) {
        int e = l * 256 + w * 64 + lane;
        int row = e >> 3, slot = e & 7;
        int sl = slot ^ (row & 7);
        long p = (long)(959 - q0 + row);
        gload16(pb_g + p * INNER_ + hd + sl * 8, &sP[0][4096 + (l * 256 + w * 64) * 8]);
    }
    stage_chunk(0, 0);
    __syncthreads();

    // ---- ring prologue (rotated by qq) ----
    #pragma unroll
    for (int n = 0; n < 4; ++n) {
        f32x4 bdv = {0.f, 0.f, 0.f, 0.f};
        #pragma unroll
        for (int ki = 0; ki < 2; ++ki) {
            int prow = n * 16 + ln15;
            int sl = (ki * 4 + g4) ^ (prow & 7);
            bf16x8 pf = *(const bf16x8*)&sP[0][4096 + prow * 64 + sl * 8];
            bdv = mfma16(pf, fqv[ki], bdv);
        }
        #pragma unroll
        for (int r4 = 0; r4 < 4; ++r4)
            ringb[qq][(n * 16 + g4 * 4 + r4 + qq) & 127] = f2bf(bdv[r4]);
    }
    __syncthreads();   // sP[1] free for chunk-1 prefetch

    float m = -1e30f, den = 0.f;   // den is PER-THREAD (reduced in epilogue)
    f32x4 o[4];
    #pragma unroll
    for (int i = 0; i < 4; ++i) o[i] = (f32x4){0.f, 0.f, 0.f, 0.f};

    auto compute_chunk = [&](int c, int buf) {
        const int bofs = buf * 4096;
        f32x4 sc[4], bd[4];
        #pragma unroll
        for (int n = 0; n < 4; ++n) {
            sc[n] = (f32x4){0.f, 0.f, 0.f, 0.f};
            bd[n] = (f32x4){0.f, 0.f, 0.f, 0.f};
        }
        __builtin_amdgcn_s_setprio(1);
        #pragma unroll
        for (int ki = 0; ki < 2; ++ki)
            #pragma unroll
            for (int n = 0; n < 4; ++n) {
                int krow = n * 16 + ln15;
                int sl = (ki * 4 + g4) ^ (krow & 7);
                bf16x8 kf = *(const bf16x8*)&sK[0][bofs + krow * 64 + sl * 8];
                sc[n] = mfma16(kf, fqu[ki], sc[n]);
                bf16x8 pf = *(const bf16x8*)&sP[0][bofs + krow * 64 + sl * 8];
                bd[n] = mfma16(pf, fqv[ki], bd[n]);
            }
        __builtin_amdgcn_s_setprio(0);

        // ring write (rotated; f2bf)
        const int pbase = (c & 1) ? 0 : 64;
        #pragma unroll
        for (int n = 0; n < 4; ++n)
            #pragma unroll
            for (int r4 = 0; r4 < 4; ++r4)
                ringb[qq][(pbase + n * 16 + g4 * 4 + r4 + qq) & 127] = f2bf(bd[n][r4]);

        // scores + per-thread tree max (v_max3-friendly shape)
        float s[4][4];
        float nm[4];
        #pragma unroll
        for (int n = 0; n < 4; ++n) {
            const int st2 = (c * 64 + 64 + n * 16 + g4 * 4) & 127;
            u16x4 rv = *(const u16x4*)&ringb[qq][st2];
            #pragma unroll
            for (int r4 = 0; r4 < 4; ++r4)
                s[n][r4] = sc[n][r4] + bf2f(rv[r4]);
            nm[n] = fmaxf(fmaxf(s[n][0], s[n][1]), fmaxf(s[n][2], s[n][3]));
        }
        float mx = fmaxf(fmaxf(nm[0], nm[1]), fmaxf(nm[2], nm[3]));

        // defer-max: __all over per-thread maxes == row-max predicate;
        // row shuffles only when rescale actually fires (wave-uniform branch)
        if (!__all(mx - m <= DEFER_THR)) {
            float mxr = fmaxf(mx, __shfl_xor(mx, 16));
            mxr = fmaxf(mxr, __shfl_xor(mxr, 32));
            float newm = fmaxf(m, mxr);
            float scl = __builtin_amdgcn_exp2f(m - newm);   // finite args
            m = newm;
            den *= scl;
            #pragma unroll
            for (int n2 = 0; n2 < 4; ++n2) {
                o[n2][0] *= scl; o[n2][1] *= scl;
                o[n2][2] *= scl; o[n2][3] *= scl;
            }
        }
        float ls = 0.f;
        #pragma unroll
        for (int n = 0; n < 4; ++n) {
            u16x4 pv4;
            #pragma unroll
            for (int r4 = 0; r4 < 4; ++r4) {
                float p = __builtin_amdgcn_exp2f(s[n][r4] - m);  // <= 2^THR = e^8
                ls += p;
                pv4[r4] = f2bf(p);
            }
            *(u16x4*)&sProb[qq][n * 16 + g4 * 4] = pv4;
        }
        den += ls;   // per-thread; no per-chunk shuffles

        // PV
        __builtin_amdgcn_s_setprio(1);
        #pragma unroll
        for (int ki = 0; ki < 2; ++ki) {
            bf16x8 pa = *(const bf16x8*)&sProb[qq][ki * 32 + g4 * 8];
            #pragma unroll
            for (int n2 = 0; n2 < 4; ++n2) {
                int drow = n2 * 16 + ln15;
                int sl = (ki * 4 + g4) ^ (drow & 7);
                bf16x8 vf = *(const bf16x8*)&sV[0][bofs + drow * 64 + sl * 8];
                o[n2] = mfma16(vf, pa, o[n2]);
            }
        }
        __builtin_amdgcn_s_setprio(0);
    };

    // ---- main loop (r10/r14-proven): stage(c+1) -> compute(c) -> barrier ----
    for (int c2 = 0; c2 < 8; ++c2) {
        int c = c2 * 2;
        stage_chunk(c + 1, 1);
        compute_chunk(c, 0);
        __syncthreads();
        if (c2 < 7) stage_chunk(c + 2, 0);
        compute_chunk(c + 1, 1);
        __syncthreads();
    }

    // epilogue: row-reduce den once (4 k-group lanes share a q-row)
    den += __shfl_xor(den, 16);
    den += __shfl_xor(den, 32);
    const float inv = 1.0f / den;
    #pragma unroll
    for (int n2 = 0; n2 < 4; ++n2) {
        u16x4 hv;
        #pragma unroll
        for (int r4 = 0; r4 < 4; ++r4)
            hv[r4] = f2bf(o[n2][r4] * inv);
        size_t oidx = (tok0 + q0 + qq) * INNER_ + hd + n2 * 16 + g4 * 4;
        *(u16x4*)(atth + oidx) = hv;
    }
}

// ---------------------------------------------------------------------------
extern "C" void kernel_launch(void* const* d_in, const int* in_sizes, int n_in,
                              void* d_out, int out_size, void* d_ws, size_t ws_size,
                              hipStream_t stream)
{
    const float* x     = (const float*)d_in[0];
    const float* pos   = (const float*)d_in[1];
    const float* w_qkv = (const float*)d_in[2];
    const float* w_q   = (const float*)d_in[3];
    const float* b_q   = (const float*)d_in[4];
    const float* w_k   = (const float*)d_in[5];
    const float* b_k   = (const float*)d_in[6];
    const float* w_v   = (const float*)d_in[7];
    const float* b_v   = (const float*)d_in[8];
    const float* w_pos = (const float*)d_in[9];
    const float* bu    = (const float*)d_in[10];
    const float* bv    = (const float*)d_in[11];
    const float* w_ao  = (const float*)d_in[12];
    const float* b_ao  = (const float*)d_in[13];
    const float* w_o   = (const float*)d_in[14];
    const float* b_o   = (const float*)d_in[15];
    float* out = (float*)d_out;

    unsigned short* u = (unsigned short*)d_ws;
    const size_t SZ = (size_t)BT_ * INNER_;          // 4,194,304
    unsigned short* xh   = u;
    unsigned short* xl   = xh + SZ;                  // (unused)
    unsigned short* qu   = xl + SZ;
    unsigned short* qv   = qu + SZ;
    unsigned short* kb   = qv + SZ;
    unsigned short* vt   = kb + SZ;
    unsigned short* atth = vt + SZ;
    unsigned short* attl = atth + SZ;                // (unused)
    unsigned short* pb_base = attl + SZ;             // 512 slack + 2047*512
    unsigned short* pb0  = pb_base + 512;
    unsigned short* posh = pb_base + 1049600;
    unsigned short* posl = posh + 1049600;           // (unused)
    unsigned short* wqkvh = posl + 1049600;
    unsigned short* wqkvl = wqkvh + 786432;
    unsigned short* waoh  = wqkvl + 786432;
    unsigned short* waol  = waoh + 262144;
    unsigned short* w5    = waol + 262144;   // wq,wk,wv,wo,wp (h,l)
    unsigned short* wq_h = w5;              unsigned short* wq_l = w5 + 262144;
    unsigned short* wk_h = w5 + 2*262144;   unsigned short* wk_l = w5 + 3*262144;
    unsigned short* wv_h = w5 + 4*262144;   unsigned short* wv_l = w5 + 5*262144;
    unsigned short* wo_h = w5 + 6*262144;   unsigned short* wo_l = w5 + 7*262144;
    unsigned short* wp_h = w5 + 8*262144;   unsigned short* wp_l = w5 + 9*262144;
    unsigned short* wcat_h = w5 + 10*262144;         // [1536][512] eff q|k|v ^T
    unsigned short* wcat_l = wcat_h + 786432;
    unsigned short* woe_h  = wcat_l + 786432;
    unsigned short* woe_l  = woe_h + 262144;
    float* beff = (float*)(woe_l + 262144);

    dim3 blk(256);

    // 1) ALL preps in one dispatch (splits + weight transpose + bias_eff + pb0)
    PrepAll pa;
    pa.s[0] = x;     pa.h[0] = xh;    pa.l[0] = xl;    pa.n[0] = (long)SZ;          pa.wantl[0] = 0;
    pa.s[1] = w_qkv; pa.h[1] = wqkvh; pa.l[1] = wqkvl; pa.n[1] = 786432L;           pa.wantl[1] = 1;
    pa.s[2] = w_ao;  pa.h[2] = waoh;  pa.l[2] = waol;  pa.n[2] = 262144L;           pa.wantl[2] = 1;
    pa.s[3] = pos;   pa.h[3] = posh;  pa.l[3] = posl;  pa.n[3] = (long)PLEN_ * 512; pa.wantl[3] = 0;
    pa.w[0] = w_q;   pa.wh[0] = wq_h; pa.wl[0] = wq_l;
    pa.w[1] = w_k;   pa.wh[1] = wk_h; pa.wl[1] = wk_l;
    pa.w[2] = w_v;   pa.wh[2] = wv_h; pa.wl[2] = wv_l;
    pa.w[3] = w_o;   pa.wh[3] = wo_h; pa.wl[3] = wo_l;
    pa.w[4] = w_pos; pa.wh[4] = wp_h; pa.wl[4] = wp_l;
    pa.b_ao = b_ao; pa.w_o = w_o; pa.b_o = b_o; pa.be = beff; pa.pb_base = pb_base;
    prep_all<<<dim3(4096, 5), blk, 0, stream>>>(pa);

    // 2) transposed effective weights (64x64 tiles, 256 blocks)
    WeffT wt;
    wt.ah[0] = wq_h; wt.al[0] = wq_l;
    wt.ah[1] = wk_h; wt.al[1] = wk_l;
    wt.ah[2] = wv_h; wt.al[2] = wv_l;
    wt.ah[3] = wo_h; wt.al[3] = wo_l;
    wt.wh[0] = wqkvh;        wt.wl[0] = wqkvl;        wt.ldw[0] = 1536;
    wt.wh[1] = wqkvh + 512;  wt.wl[1] = wqkvl + 512;  wt.ldw[1] = 1536;
    wt.wh[2] = wqkvh + 1024; wt.wl[2] = wqkvl + 1024; wt.ldw[2] = 1536;
    wt.wh[3] = waoh;         wt.wl[3] = waol;         wt.ldw[3] = 512;
    wt.ch[0] = wcat_h;            wt.cl[0] = wcat_l;
    wt.ch[1] = wcat_h + 262144;   wt.cl[1] = wcat_l + 262144;
    wt.ch[2] = wcat_h + 2*262144; wt.cl[2] = wcat_l + 2*262144;
    wt.ch[3] = woe_h;             wt.cl[3] = woe_l;
    gemm_wefft<<<dim3(8, 8, 4), blk, 0, stream>>>(wt);

    // 3) merged q/k/v + pos projection (1D grid, XCD row-contiguous swizzle)
    gemm_qkvp<<<dim3(832), blk, 0, stream>>>(xh, wcat_h, wcat_l,
        posh, wp_h, wp_l,
        b_q, bu, bv, b_k, b_v, qu, qv, kb, vt, pb0);

    // 4) attention (exp2 softmax, per-thread den, deferred shuffles)
    attn_v18<<<1024, blk, 0, stream>>>(qu, qv, kb, vt, pb0, atth);

    // 5) output GEMM (2-term, 1D grid, XCD row-contiguous swizzle)
    gemm_out<<<dim3(512), blk, 0, stream>>>(atth, woe_h, woe_l, beff, out);
}